// Round 6
// baseline (2771.019 us; speedup 1.0000x reference)
//
#include <hip/hip_runtime.h>
#include <math.h>

#define BB 4
#define TT 4096
#define DIMW 1024
#define HID 1536
#define HID2 3072
#define KC 4
#define SSEG 16
#define LSEG 256
#define DD 384
#define NCH 64          // scan chunks per batch
#define CHL 64          // tokens per chunk (NCH*CHL == TT)
#define TH  ((size_t)TT*(size_t)HID)   // elements in one T x HID slot

typedef _Float16 h8 __attribute__((ext_vector_type(8)));
typedef float f4 __attribute__((ext_vector_type(4)));

#define RSCL 4.8828125e-4f   // 2^-11

// fp16 2-plane split with scaled residual: a ~= h0 + h1 * 2^-11.
__device__ __forceinline__ void hsplit(float a, _Float16& h0, _Float16& h1)
{
    _Float16 t = (_Float16)a;
    float tf = (float)t;
    if (fabsf(tf) < 6.103515625e-05f) { t = (_Float16)0.f; tf = 0.f; }
    h0 = t;
    h1 = (_Float16)((a - tf) * 2048.0f);
}

// async global->LDS, 16B per lane
__device__ __forceinline__ void gl_lds16(const _Float16* g, _Float16* l)
{
    __builtin_amdgcn_global_load_lds(
        (const __attribute__((address_space(1))) unsigned int*)g,
        (__attribute__((address_space(3))) unsigned int*)l,
        16, 0, 0);
}

// =====================================================================
// LDS-transpose split: fp32 [R][Kd] -> 2 fp16 planes kcm (weights + xb)
// =====================================================================
__global__ __launch_bounds__(256) void split2t(const float* __restrict__ src,
                                               _Float16* __restrict__ dst,
                                               int R, int Kd, size_t ps)
{
    __shared__ float tile[64][65];
    const int tid = threadIdx.x;
    const int bx = blockIdx.x;
    const int by = blockIdx.y;
    {
        const int lr = tid >> 2;
        const int lc = (tid & 3) * 16;
        const float* s = src + (size_t)(by * 64 + lr) * Kd + bx * 64 + lc;
#pragma unroll
        for (int e = 0; e < 16; e++) tile[lr][lc + e] = s[e];
    }
    __syncthreads();
    const int c = tid >> 5;
    const int r0 = tid & 31;
#pragma unroll
    for (int rr = 0; rr < 2; rr++) {
        const int r = r0 + rr * 32;
        h8 h0v, h1v;
#pragma unroll
        for (int e = 0; e < 8; e++) {
            _Float16 a0, a1;
            hsplit(tile[r][c * 8 + e], a0, a1);
            h0v[e] = a0; h1v[e] = a1;
        }
        const size_t didx = ((size_t)(bx * 8 + c) * R + by * 64 + r) * 8;
        *(h8*)(dst + didx) = h0v;
        *(h8*)(dst + ps + didx) = h1v;
    }
}

// concat wk|wv -> fp32 (2DD x HID), once
__global__ __launch_bounds__(256) void catkv_kernel(const float* __restrict__ wk,
                                                    const float* __restrict__ wv,
                                                    float* __restrict__ wkv)
{
    const int half = DD * HID;
    int i = blockIdx.x * 256 + threadIdx.x;
    if (i < half) wkv[i] = wk[i];
    else if (i < 2 * half) wkv[i] = wv[i - half];
}

// =====================================================================
// PIPELINED fp16x2 MFMA GEMM (3-buffer LDS, counted vmcnt, 1 barrier/K-step)
// 8 waves (2x4), wave tile (TM/2)x(TN/4), BK=32, DUAL accumulators.
// Per K-step: wait vmcnt(PW) [stage t done, t+1 in flight] -> s_barrier ->
// issue stage t+2 -> ds_read + MFMA on buf t%3.  Loads are NEVER drained
// to 0 inside the loop (T3+T4 pattern).
// =====================================================================
template<int MODE, int TM, int TN>
__global__ __launch_bounds__(512, 2) void gemm_pipe(
    const _Float16* __restrict__ Ap, size_t aps,
    const _Float16* __restrict__ Wp, size_t wps,
    float* __restrict__ C0, float* __restrict__ C1,
    const float* __restrict__ X,
    _Float16* __restrict__ OP, size_t ops,
    int M, int Nout, int Kd)
{
    constexpr int WTM = TM / 2, WTN = TN / 4;
    constexpr int MI = WTM / 16, NI = WTN / 16;
    static_assert(MI * NI <= 16, "DUAL path only");
    constexpr int API = TM / 16;
    constexpr int BPI = TN / 16;
    constexpr int ATOT = 2 * API;
    constexpr int NISS = ATOT + 2 * BPI;
    static_assert(NISS % 8 == 0, "issues must divide 8 waves");
    constexpr int PW = NISS / 8;          // per-wave loads per stage

    __shared__ _Float16 Als[3][2][TM * 32];
    __shared__ _Float16 Bls[3][2][TN * 32];

    const int tid = threadIdx.x;
    const int lane = tid & 63;
    const int wv = tid >> 6;
    const int wr = wv >> 2, wc = wv & 3;
    const int lr = lane & 15, lg = lane >> 4;

    int bx = blockIdx.x, by = blockIdx.y;
    {
        const int gx = gridDim.x;
        const int nwg = gx * gridDim.y;
        if ((nwg & 7) == 0) {
            int wg = by * gx + bx;
            wg = (wg & 7) * (nwg >> 3) + (wg >> 3);
            bx = wg % gx; by = wg / gx;
        }
    }
    const int m0 = bx * TM, n0 = by * TN;

    f4 acc1[MI][NI], acc2[MI][NI];
#pragma unroll
    for (int i = 0; i < MI; i++)
#pragma unroll
        for (int j = 0; j < NI; j++) {
            acc1[i][j] = (f4){0.f, 0.f, 0.f, 0.f};
            acc2[i][j] = (f4){0.f, 0.f, 0.f, 0.f};
        }

    auto stage = [&](int ts) {
        const int kq0 = ts * 4;
        const int buf = ts % 3;
#pragma unroll
        for (int j = 0; j < PW; j++) {
            const int i = j * 8 + wv;
            if (i < ATOT) {
                const int pl = i / API, s = i - pl * API;
                const int kc = (s * 64) / TM, r0 = (s * 64) % TM;
                gl_lds16(Ap + pl * aps + ((size_t)(kq0 + kc) * M + m0 + r0) * 8 + lane * 8,
                         &Als[buf][pl][(kc * TM + r0) * 8]);
            } else {
                const int jj = i - ATOT;
                const int pl = jj / BPI, s = jj - pl * BPI;
                const int kc = (s * 64) / TN, r0 = (s * 64) % TN;
                gl_lds16(Wp + pl * wps + ((size_t)(kq0 + kc) * Nout + n0 + r0) * 8 + lane * 8,
                         &Bls[buf][pl][(kc * TN + r0) * 8]);
            }
        }
    };

    const int NS = Kd / 32;
    stage(0);
    stage(1);

    for (int t = 0; t < NS; t++) {
        // stage(t) must be complete; stage(t+1)'s PW loads may stay in flight.
        if (t + 1 < NS) asm volatile("s_waitcnt vmcnt(%0)" :: "i"(PW) : "memory");
        else            asm volatile("s_waitcnt vmcnt(0)" ::: "memory");
        __builtin_amdgcn_s_barrier();
        if (t + 2 < NS) stage(t + 2);   // into buf (t+2)%3, fully read by all waves

        const int buf = t % 3;
        h8 af0[MI], af1[MI];
#pragma unroll
        for (int mi = 0; mi < MI; mi++) {
            const int arow = wr * WTM + mi * 16 + lr;
            af0[mi] = *(const h8*)&Als[buf][0][(lg * TM + arow) * 8];
            af1[mi] = *(const h8*)&Als[buf][1][(lg * TM + arow) * 8];
        }
#pragma unroll
        for (int ni = 0; ni < NI; ni++) {
            const int brow = wc * WTN + ni * 16 + lr;
            h8 b0 = *(const h8*)&Bls[buf][0][(lg * TN + brow) * 8];
            h8 b1 = *(const h8*)&Bls[buf][1][(lg * TN + brow) * 8];
#pragma unroll
            for (int mi = 0; mi < MI; mi++) {
                acc1[mi][ni] = __builtin_amdgcn_mfma_f32_16x16x32_f16(af0[mi], b0, acc1[mi][ni], 0, 0, 0);
                acc2[mi][ni] = __builtin_amdgcn_mfma_f32_16x16x32_f16(af1[mi], b0, acc2[mi][ni], 0, 0, 0);
                acc2[mi][ni] = __builtin_amdgcn_mfma_f32_16x16x32_f16(af0[mi], b1, acc2[mi][ni], 0, 0, 0);
            }
        }
    }

#pragma unroll
    for (int mi = 0; mi < MI; mi++) {
#pragma unroll
        for (int ni = 0; ni < NI; ni++) {
#pragma unroll
            for (int r = 0; r < 4; r++) {
                const float v = acc1[mi][ni][r] + acc2[mi][ni][r] * RSCL;
                const int m = m0 + wr * WTM + mi * 16 + lg * 4 + r;
                const int n = n0 + wc * WTN + ni * 16 + lr;
                if constexpr (MODE == 1) {
                    if (n < HID) C0[(size_t)m * HID + n] = v;
                    else         C1[(size_t)m * HID + (n - HID)] = v;
                } else if constexpr (MODE == 2) {
                    float g = v;
                    float fv = (g / (1.0f + expf(-g))) * X[(size_t)m * Nout + n];
                    C0[(size_t)m * Nout + n] = fv;
                    _Float16 a0, a1;
                    hsplit(fv, a0, a1);
                    const size_t didx = ((size_t)(n >> 3) * M + m) * 8 + (n & 7);
                    OP[didx] = a0;
                    OP[ops + didx] = a1;
                } else {
                    C0[(size_t)m * Nout + n] = v;
                }
            }
        }
    }
}

// =====================================================================
// 2-buffer fp16x2 MFMA GEMM (round-4 proven) for kv / rq / out
// =====================================================================
template<int MODE, int TM, int TN, int WRN, int WCN>
__global__ __launch_bounds__(WRN * WCN * 64, 2) void gemm_mfma(
    const _Float16* __restrict__ Ap, size_t aps,
    const _Float16* __restrict__ Wp, size_t wps,
    float* __restrict__ C0, float* __restrict__ C1,
    const float* __restrict__ X,
    _Float16* __restrict__ OP, size_t ops,
    int M, int Nout, int Kd)
{
    constexpr int NWAVE = WRN * WCN;
    constexpr int WTM = TM / WRN, WTN = TN / WCN;
    constexpr int MI = WTM / 16, NI = WTN / 16;
    constexpr int API = TM / 16;
    constexpr int BPI = TN / 16;
    constexpr int ATOT = 2 * API;
    constexpr int NISS = ATOT + 2 * BPI;
    static_assert(NISS % NWAVE == 0, "issue count must divide waves");
    static_assert(MI * NI <= 16, "DUAL only");

    __shared__ _Float16 Als[2][2][TM * 32];
    __shared__ _Float16 Bls[2][2][TN * 32];

    const int tid = threadIdx.x;
    const int lane = tid & 63;
    const int wv = tid >> 6;
    const int wr = wv / WCN, wc = wv % WCN;
    const int lr = lane & 15, lg = lane >> 4;

    int bx = blockIdx.x, by = blockIdx.y;
    {
        const int gx = gridDim.x;
        const int nwg = gx * gridDim.y;
        if ((nwg & 7) == 0) {
            int wg = by * gx + bx;
            wg = (wg & 7) * (nwg >> 3) + (wg >> 3);
            bx = wg % gx; by = wg / gx;
        }
    }
    const int m0 = bx * TM, n0 = by * TN;

    f4 acc1[MI][NI], acc2[MI][NI];
#pragma unroll
    for (int i = 0; i < MI; i++)
#pragma unroll
        for (int j = 0; j < NI; j++) {
            acc1[i][j] = (f4){0.f, 0.f, 0.f, 0.f};
            acc2[i][j] = (f4){0.f, 0.f, 0.f, 0.f};
        }

    auto stage = [&](int kq0, int buf) {
#pragma unroll
        for (int j = 0; j < NISS / NWAVE; j++) {
            const int i = j * NWAVE + wv;
            if (i < ATOT) {
                const int pl = i / API, s = i - pl * API;
                const int kc = (s * 64) / TM, r0 = (s * 64) % TM;
                gl_lds16(Ap + pl * aps + ((size_t)(kq0 + kc) * M + m0 + r0) * 8 + lane * 8,
                         &Als[buf][pl][(kc * TM + r0) * 8]);
            } else {
                const int jj = i - ATOT;
                const int pl = jj / BPI, s = jj - pl * BPI;
                const int kc = (s * 64) / TN, r0 = (s * 64) % TN;
                gl_lds16(Wp + pl * wps + ((size_t)(kq0 + kc) * Nout + n0 + r0) * 8 + lane * 8,
                         &Bls[buf][pl][(kc * TN + r0) * 8]);
            }
        }
    };

    stage(0, 0);
    __syncthreads();

    const int NS = Kd / 32;
    for (int t = 0; t < NS; t++) {
        const int buf = t & 1;
        if (t + 1 < NS) stage((t + 1) * 4, buf ^ 1);

        h8 af0[MI], af1[MI];
#pragma unroll
        for (int mi = 0; mi < MI; mi++) {
            const int arow = wr * WTM + mi * 16 + lr;
            af0[mi] = *(const h8*)&Als[buf][0][(lg * TM + arow) * 8];
            af1[mi] = *(const h8*)&Als[buf][1][(lg * TM + arow) * 8];
        }
#pragma unroll
        for (int ni = 0; ni < NI; ni++) {
            const int brow = wc * WTN + ni * 16 + lr;
            h8 b0 = *(const h8*)&Bls[buf][0][(lg * TN + brow) * 8];
            h8 b1 = *(const h8*)&Bls[buf][1][(lg * TN + brow) * 8];
#pragma unroll
            for (int mi = 0; mi < MI; mi++) {
                acc1[mi][ni] = __builtin_amdgcn_mfma_f32_16x16x32_f16(af0[mi], b0, acc1[mi][ni], 0, 0, 0);
                acc2[mi][ni] = __builtin_amdgcn_mfma_f32_16x16x32_f16(af1[mi], b0, acc2[mi][ni], 0, 0, 0);
                acc2[mi][ni] = __builtin_amdgcn_mfma_f32_16x16x32_f16(af0[mi], b1, acc2[mi][ni], 0, 0, 0);
            }
        }
        __syncthreads();
    }

#pragma unroll
    for (int mi = 0; mi < MI; mi++) {
#pragma unroll
        for (int ni = 0; ni < NI; ni++) {
#pragma unroll
            for (int r = 0; r < 4; r++) {
                const float v = acc1[mi][ni][r] + acc2[mi][ni][r] * RSCL;
                const int m = m0 + wr * WTM + mi * 16 + lg * 4 + r;
                const int n = n0 + wc * WTN + ni * 16 + lr;
                if constexpr (MODE == 1) {
                    if (n < HID) C0[(size_t)m * HID + n] = v;
                    else         C1[(size_t)m * HID + (n - HID)] = v;
                } else if constexpr (MODE == 2) {
                    float g = v;
                    float fv = (g / (1.0f + expf(-g))) * X[(size_t)m * Nout + n];
                    C0[(size_t)m * Nout + n] = fv;
                    _Float16 a0, a1;
                    hsplit(fv, a0, a1);
                    const size_t didx = ((size_t)(n >> 3) * M + m) * 8 + (n & 7);
                    OP[didx] = a0;
                    OP[ops + didx] = a1;
                } else {
                    C0[(size_t)m * Nout + n] = v;
                }
            }
        }
    }
}

// =====================================================================
// fp32 VALU GEMM kept only for tiny M=16 matmuls (q, rk, rv)
// =====================================================================
template<int MODE, int TM, int TN>
__global__ __launch_bounds__(256) void gemm32(const float* __restrict__ A,
                                              const float* __restrict__ W,
                                              float* __restrict__ C0,
                                              float* __restrict__ C1,
                                              const float* __restrict__ X,
                                              int M, int Nout, int Kd)
{
    constexpr int GM = TM / 64;
    constexpr int GN = TN / 64;
    constexpr int AF4 = TM * 4;
    constexpr int WF4 = TN * 4;
    constexpr int ALOOP = (AF4 + 255) / 256;
    constexpr int WLOOP = (WF4 + 255) / 256;

    __shared__ float As[16][TM];
    __shared__ float Bs[16][TN];

    const int tid = threadIdx.x;
    const int m0 = blockIdx.x * TM;
    const int n0 = blockIdx.y * TN;
    const int tx = tid & 15, ty = tid >> 4;

    float acc[GM * 4][GN * 4];
#pragma unroll
    for (int i = 0; i < GM * 4; i++)
#pragma unroll
        for (int j = 0; j < GN * 4; j++) acc[i][j] = 0.0f;

    float4 aReg[ALOOP], wReg[WLOOP];

    auto issueLoads = [&](int k0) {
#pragma unroll
        for (int u = 0; u < ALOOP; u++) {
            const int idx = tid + u * 256;
            float4 v = make_float4(0.f, 0.f, 0.f, 0.f);
            if (idx < AF4) {
                const int row = idx >> 2, kq = (idx & 3) * 4;
                const long ar = (long)(m0 + row);
                if (ar < M) v = *(const float4*)(A + ar * (long)Kd + (k0 + kq));
            }
            aReg[u] = v;
        }
#pragma unroll
        for (int u = 0; u < WLOOP; u++) {
            const int idx = tid + u * 256;
            float4 v = make_float4(0.f, 0.f, 0.f, 0.f);
            if (idx < WF4) {
                const int row = idx >> 2, kq = (idx & 3) * 4;
                const long wr = (long)(n0 + row);
                v = *(const float4*)(W + wr * (long)Kd + (k0 + kq));
            }
            wReg[u] = v;
        }
    };
    auto writeLDS = [&]() {
#pragma unroll
        for (int u = 0; u < ALOOP; u++) {
            const int idx = tid + u * 256;
            if (idx < AF4) {
                const int row = idx >> 2, kq = (idx & 3) * 4;
                As[kq + 0][row] = aReg[u].x;
                As[kq + 1][row] = aReg[u].y;
                As[kq + 2][row] = aReg[u].z;
                As[kq + 3][row] = aReg[u].w;
            }
        }
#pragma unroll
        for (int u = 0; u < WLOOP; u++) {
            const int idx = tid + u * 256;
            if (idx < WF4) {
                const int row = idx >> 2, kq = (idx & 3) * 4;
                Bs[kq + 0][row] = wReg[u].x;
                Bs[kq + 1][row] = wReg[u].y;
                Bs[kq + 2][row] = wReg[u].z;
                Bs[kq + 3][row] = wReg[u].w;
            }
        }
    };

    issueLoads(0);
    writeLDS();
    __syncthreads();

    const int NT = Kd / 16;
    for (int t = 0; t < NT; t++) {
        if (t + 1 < NT) issueLoads((t + 1) * 16);
#pragma unroll
        for (int k = 0; k < 16; k++) {
            float a[GM * 4], b[GN * 4];
#pragma unroll
            for (int g = 0; g < GM; g++) {
                const float4 t4 = *(const float4*)&As[k][g * 64 + ty * 4];
                a[g * 4 + 0] = t4.x; a[g * 4 + 1] = t4.y;
                a[g * 4 + 2] = t4.z; a[g * 4 + 3] = t4.w;
            }
#pragma unroll
            for (int g = 0; g < GN; g++) {
                const float4 t4 = *(const float4*)&Bs[k][g * 64 + tx * 4];
                b[g * 4 + 0] = t4.x; b[g * 4 + 1] = t4.y;
                b[g * 4 + 2] = t4.z; b[g * 4 + 3] = t4.w;
            }
#pragma unroll
            for (int i = 0; i < GM * 4; i++)
#pragma unroll
                for (int j = 0; j < GN * 4; j++) acc[i][j] += a[i] * b[j];
        }
        __syncthreads();
        if (t + 1 < NT) {
            writeLDS();
            __syncthreads();
        }
    }

#pragma unroll
    for (int i = 0; i < GM * 4; i++) {
        const int m = m0 + (i >> 2) * 64 + ty * 4 + (i & 3);
        if (m >= M) continue;
#pragma unroll
        for (int j = 0; j < GN * 4; j++) {
            const int n = n0 + (j >> 2) * 64 + tx * 4 + (j & 3);
            if (n >= Nout) continue;
            C0[(long)m * Nout + n] = acc[i][j];
        }
    }
}

// softplus(forget_base) per channel (once) -- double (feeds sensitive alpha path)
__global__ __launch_bounds__(256) void spb_kernel(const float* __restrict__ fb,
                                                  double* __restrict__ spb)
{
    int h = blockIdx.x * 256 + threadIdx.x;
    if (h < HID) {
        double xv = (double)fb[h];
        spb[h] = log1p(exp(xv));
    }
}

// causal depthwise conv (one batch), fp32 math, fused fp16-plane split
__global__ __launch_bounds__(256) void conv_kernel(const float* __restrict__ xin,
                                                   const float* __restrict__ cw,
                                                   const float* __restrict__ cb,
                                                   float* __restrict__ outp,
                                                   _Float16* __restrict__ outP,
                                                   size_t ps)
{
    size_t i = (size_t)blockIdx.x * 256 + threadIdx.x;
    if (i >= TH) return;
    int h = (int)(i % HID);
    int t = (int)(i / HID);
    float acc = cb[h];
#pragma unroll
    for (int j = 0; j < KC; j++) {
        int tt = t - (KC - 1) + j;
        if (tt >= 0) acc = fmaf(cw[h * KC + j], xin[(size_t)tt * HID + h], acc);
    }
    outp[i] = acc;
    _Float16 a0, a1;
    hsplit(acc, a0, a1);
    const size_t didx = ((size_t)(h >> 3) * TT + t) * 8 + (h & 7);
    outP[didx] = a0;
    outP[ps + didx] = a1;
}

// forget/inp (+bias) -> alpha, xh2.  alpha path double (scan amplifies),
// input-gate path fp32.
__global__ __launch_bounds__(256) void alpha_xh2_kernel(float* __restrict__ fg,
                                                        float* __restrict__ ip,
                                                        const float* __restrict__ xh1,
                                                        const double* __restrict__ spb,
                                                        const float* __restrict__ gb)
{
    size_t i = (size_t)blockIdx.x * 256 + threadIdx.x;
    if (i >= TH) return;
    int h = (int)(i % HID);
    double f  = (double)fg[i] + (double)gb[h];
    float g2 = ip[i] + gb[HID + h];
    double sigf = 1.0 / (1.0 + exp(-f));
    float alpha = (float)exp(-8.0 * spb[h] * sigf);
    float s2 = sqrtf(1.0f - alpha * alpha + 1e-6f);
    float sigi = 1.0f / (1.0f + expf(-g2));
    fg[i] = alpha;
    ip[i] = s2 * sigi * xh1[i];
}

// scan pass1 (double accumulation)
__global__ __launch_bounds__(256) void scan1_kernel(const float* __restrict__ alpha,
                                                    const float* __restrict__ xh2,
                                                    double* __restrict__ cA,
                                                    double* __restrict__ cB)
{
    int idx = blockIdx.x * 256 + threadIdx.x;
    if (idx >= NCH * HID) return;
    int h = idx % HID;
    int c = idx / HID;
    size_t base = (size_t)c * CHL * HID + h;
    double aP = 1.0, bV = 0.0;
    for (int i = 0; i < CHL; i++) {
        double a  = (double)alpha[base + (size_t)i * HID];
        double xv = (double)xh2 [base + (size_t)i * HID];
        bV = a * bV + xv;
        aP *= a;
    }
    size_t o = (size_t)c * HID + h;
    cA[o] = aP;
    cB[o] = bV;
}

// scan pass2
__global__ __launch_bounds__(256) void scan2_kernel(const double* __restrict__ cA,
                                                    const double* __restrict__ cB,
                                                    double* __restrict__ cH0)
{
    int h = blockIdx.x * 256 + threadIdx.x;
    if (h >= HID) return;
    double carry = 0.0;
    for (int c = 0; c < NCH; c++) {
        size_t o = (size_t)c * HID + h;
        cH0[o] = carry;
        carry = cA[o] * carry + cB[o];
    }
}

// scan pass3
__global__ __launch_bounds__(256) void scan3_kernel(const float* __restrict__ alpha,
                                                    const float* __restrict__ xh2,
                                                    const double* __restrict__ cH0,
                                                    float* __restrict__ hout)
{
    int idx = blockIdx.x * 256 + threadIdx.x;
    if (idx >= NCH * HID) return;
    int h = idx % HID;
    int c = idx / HID;
    size_t base = (size_t)c * CHL * HID + h;
    double hv = cH0[(size_t)c * HID + h];
    for (int i = 0; i < CHL; i++) {
        double a  = (double)alpha[base + (size_t)i * HID];
        double xv = (double)xh2 [base + (size_t)i * HID];
        hv = a * hv + xv;
        hout[base + (size_t)i * HID] = (float)hv;
    }
}

// xr = gelu_exact(xh3)*h, fp32 math, fused fp16-plane split
__global__ __launch_bounds__(256) void gelu_mul_kernel(float* __restrict__ xh3,
                                                       const float* __restrict__ hbuf,
                                                       _Float16* __restrict__ outP,
                                                       size_t ps)
{
    size_t i = (size_t)blockIdx.x * 256 + threadIdx.x;
    if (i >= TH) return;
    int h = (int)(i % HID);
    int t = (int)(i / HID);
    float x3 = xh3[i];
    float ge = 0.5f * x3 * (1.0f + erff(x3 * 0.70710678f));
    float fv = ge * hbuf[i];
    xh3[i] = fv;
    _Float16 a0, a1;
    hsplit(fv, a0, a1);
    const size_t didx = ((size_t)(h >> 3) * TT + t) * 8 + (h & 7);
    outP[didx] = a0;
    outP[ps + didx] = a1;
}

// attention 1: kv is [T][2*DD], cols [0,DD)=k, [DD,2DD)=v
__global__ __launch_bounds__(256) void attn1_kernel(const float* __restrict__ kv,
                                                    const float* __restrict__ qbuf,
                                                    float* __restrict__ mem)
{
    const int s = blockIdx.x;
    const int l = threadIdx.x;
    const size_t row = (size_t)s * LSEG + l;
    const float* kr = kv + row * (2 * DD);
    const float* qs = qbuf + (size_t)s * DD;
    double acc = 0.0;
    for (int d = 0; d < DD; d++) acc += (double)qs[d] * (double)kr[d];
    double qk = acc / sqrt((double)DD);
    __shared__ double r1[256];
    __shared__ double sw[256];
    r1[l] = qk; __syncthreads();
    for (int off = 128; off > 0; off >>= 1) {
        if (l < off) r1[l] = fmax(r1[l], r1[l + off]);
        __syncthreads();
    }
    double m = r1[0]; __syncthreads();
    double e = exp(qk - m);
    r1[l] = e; __syncthreads();
    for (int off = 128; off > 0; off >>= 1) {
        if (l < off) r1[l] += r1[l + off];
        __syncthreads();
    }
    double denom = r1[0];
    sw[l] = e / denom; __syncthreads();
    const size_t vbase = (size_t)s * LSEG * (2 * DD) + DD;
    for (int d = l; d < DD; d += 256) {
        double a2 = 0.0;
        for (int ll = 0; ll < LSEG; ll++)
            a2 += sw[ll] * (double)kv[vbase + (size_t)ll * (2 * DD) + d];
        mem[(size_t)s * DD + d] = (float)a2;
    }
}

// attention 2 + output gate; epilogue writes 2 fp16 planes (kcm) directly
__global__ __launch_bounds__(256) void attn2_kernel(const float* __restrict__ rq,
                                                    const float* __restrict__ rk,
                                                    const float* __restrict__ rv,
                                                    const float* __restrict__ xr,
                                                    const float* __restrict__ wg,
                                                    _Float16* __restrict__ outP,
                                                    size_t ps)
{
    const int t = blockIdx.x;
    const int sigma = t >> 8;
    const int tid = threadIdx.x;
    __shared__ double sqk[16];
    __shared__ double red[256];
    __shared__ double sw[16];
    __shared__ double sgate;

    const float* rqn = rq + (size_t)t * DD;
    {
        int s = tid >> 4, j = tid & 15;
        const float* rks = rk + (size_t)s * DD;
        double part = 0.0;
        for (int d = j; d < DD; d += 16) part += (double)rqn[d] * (double)rks[d];
#pragma unroll
        for (int off = 8; off > 0; off >>= 1) part += __shfl_down(part, off, 16);
        if (j == 0) sqk[s] = part;
    }
    double gp = 0.0;
    const float* xrn = xr + (size_t)t * HID;
    for (int hh = tid; hh < HID; hh += 256) gp += (double)xrn[hh] * (double)wg[hh];
    red[tid] = gp; __syncthreads();
    for (int off = 128; off > 0; off >>= 1) {
        if (tid < off) red[tid] += red[tid + off];
        __syncthreads();
    }
    if (tid == 0) {
        const double inv = 1.0 / sqrt((double)DD);
        double m = -1e300;
        for (int ss = sigma; ss < 16; ss++) {
            double v = sqk[ss] * inv;
            sqk[ss] = v;
            if (v > m) m = v;
        }
        double sum = 0.0;
        for (int ss = sigma; ss < 16; ss++) {
            double e = exp(sqk[ss] - m);
            sw[ss] = e;
            sum += e;
        }
        double isum = 1.0 / sum;
        for (int ss = 0; ss < sigma; ss++) sw[ss] = 0.0;
        for (int ss = sigma; ss < 16; ss++) sw[ss] *= isum;
        sgate = 1.0 / (1.0 + exp(-red[0]));
    }
    __syncthreads();
    const double gte = sgate;
    for (int c = tid; c < HID / 8; c += 256) {
        double accv[8] = {0, 0, 0, 0, 0, 0, 0, 0};
        for (int ss = sigma; ss < 16; ss++) {
            const float* rvp = rv + (size_t)ss * HID + c * 8;
            double w = sw[ss];
#pragma unroll
            for (int e = 0; e < 8; e++) accv[e] += w * (double)rvp[e];
        }
        h8 h0v, h1v;
#pragma unroll
        for (int e = 0; e < 8; e++) {
            _Float16 a0, a1;
            hsplit((float)(gte * accv[e]), a0, a1);
            h0v[e] = a0; h1v[e] = a1;
        }
        const size_t didx = ((size_t)c * TT + t) * 8;
        *(h8*)(outP + didx) = h0v;
        *(h8*)(outP + ps + didx) = h1v;
    }
}

extern "C" void kernel_launch(void* const* d_in, const int* in_sizes, int n_in,
                              void* d_out, int out_size, void* d_ws, size_t ws_size,
                              hipStream_t stream)
{
    const float* x            = (const float*)d_in[0];
    const float* input_w      = (const float*)d_in[1];
    const float* conv_w       = (const float*)d_in[2];
    const float* conv_b       = (const float*)d_in[3];
    const float* gates_w      = (const float*)d_in[4];
    const float* gates_b      = (const float*)d_in[5];
    const float* forget_base  = (const float*)d_in[6];
    const float* output_w     = (const float*)d_in[7];
    const float* memory_slots = (const float*)d_in[8];
    const float* wq_w         = (const float*)d_in[9];
    const float* wk_w         = (const float*)d_in[10];
    const float* wv_w         = (const float*)d_in[11];
    const float* wg_w         = (const float*)d_in[12];
    const float* rq_w         = (const float*)d_in[13];
    const float* rk_w         = (const float*)d_in[14];
    const float* rv_w         = (const float*)d_in[15];
    float* out = (float*)d_out;

    // ---- workspace layout (~165 MB) ----
    double* spb  = (double*)d_ws;                     // HID
    double* cA   = spb + HID;                         // NCH*HID
    double* cB   = cA + (size_t)NCH * HID;
    double* cH0  = cB + (size_t)NCH * HID;
    float* slotA = (float*)(cH0 + (size_t)NCH * HID); // TH floats each
    float* slotB = slotA + TH;
    float* slotC = slotB + TH;
    float* qbuf   = slotC + TH;                       // 16*384
    float* membuf = qbuf + (size_t)SSEG * DD;
    float* rkbuf  = membuf + (size_t)SSEG * DD;
    float* rvbuf  = rkbuf + (size_t)SSEG * DD;        // 16*1536

    _Float16* base_h = (_Float16*)(rvbuf + (size_t)SSEG * HID);
    const size_t iwN  = (size_t)HID * DIMW;           // per-half input_w
    const size_t gwN  = (size_t)HID2 * HID;
    const size_t kvN  = (size_t)(2 * DD) * HID;
    const size_t rqN  = (size_t)DD * HID;
    const size_t owN  = (size_t)DIMW * HID;
    const size_t xbN  = (size_t)TT * DIMW;
    _Float16* iwlo = base_h;                          // 2*iwN
    _Float16* iwhi = iwlo + 2 * iwN;
    _Float16* gwp  = iwhi + 2 * iwN;
    _Float16* wkvp = gwp  + 2 * gwN;
    _Float16* rqwp = wkvp + 2 * kvN;
    _Float16* owp  = rqwp + 2 * rqN;
    _Float16* xbP  = owp  + 2 * owN;                  // 2*xbN
    _Float16* P1   = xbP  + 2 * xbN;                  // 2*TH

    dim3 blk(256);
    dim3 blk512(512);
    const int ewBlocks = (int)(TH / 256);

    // ---- one-time: softplus, weight splits, q projection ----
    spb_kernel<<<(HID + 255) / 256, blk, 0, stream>>>(forget_base, spb);
    catkv_kernel<<<(2 * DD * HID) / 256, blk, 0, stream>>>(wk_w, wv_w, slotA);
    split2t<<<dim3(DIMW / 64, HID / 64), blk, 0, stream>>>(input_w, iwlo, HID, DIMW, iwN);
    split2t<<<dim3(DIMW / 64, HID / 64), blk, 0, stream>>>(input_w + (size_t)HID * DIMW,
                                                           iwhi, HID, DIMW, iwN);
    split2t<<<dim3(HID / 64, HID2 / 64), blk, 0, stream>>>(gates_w, gwp, HID2, HID, gwN);
    split2t<<<dim3(HID / 64, (2 * DD) / 64), blk, 0, stream>>>(slotA, wkvp, 2 * DD, HID, kvN);
    split2t<<<dim3(HID / 64, DD / 64), blk, 0, stream>>>(rq_w, rqwp, DD, HID, rqN);
    split2t<<<dim3(HID / 64, DIMW / 64), blk, 0, stream>>>(output_w, owp, DIMW, HID, owN);
    gemm32<0, 64, 64><<<dim3(1, DD / 64), blk, 0, stream>>>(
        memory_slots, wq_w, qbuf, (float*)nullptr, (const float*)nullptr, SSEG, DD, DD);

    for (int b = 0; b < BB; b++) {
        const float* xb   = x   + (size_t)b * TT * DIMW;
        float*       outb = out + (size_t)b * TT * DIMW;

        // split xb once (shared by xh0 GEMM and silu GEMM)
        split2t<<<dim3(DIMW / 64, TT / 64), blk, 0, stream>>>(xb, xbP, TT, DIMW, xbN);
        // xh0 = xb @ input_w[HID:,:].T -> slotB   (pipelined, grid 256)
        gemm_pipe<0, 128, 192><<<dim3(TT / 128, HID / 192), blk512, 0, stream>>>(
            xbP, xbN, iwhi, iwN, slotB, (float*)nullptr, (const float*)nullptr,
            (_Float16*)nullptr, 0, TT, HID, DIMW);
        // xh1 = causal conv(xh0) -> slotC fp32 + P1 planes (fused split)
        conv_kernel<<<ewBlocks, blk, 0, stream>>>(slotB, conv_w, conv_b, slotC, P1, TH);
        // g = xh1 @ gates_w.T -> forget(slotA), inp(slotB)  (pipelined, grid 512)
        gemm_pipe<1, 128, 192><<<dim3(TT / 128, HID2 / 192), blk512, 0, stream>>>(
            P1, TH, gwp, gwN, slotA, slotB, (const float*)nullptr,
            (_Float16*)nullptr, 0, TT, HID2, HID);
        // alpha(slotA), xh2(slotB), reads xh1(slotC)
        alpha_xh2_kernel<<<ewBlocks, blk, 0, stream>>>(slotA, slotB, slotC, spb, gates_b);
        // scan -> h(slotC)
        scan1_kernel<<<(NCH * HID) / 256, blk, 0, stream>>>(slotA, slotB, cA, cB);
        scan2_kernel<<<(HID + 255) / 256, blk, 0, stream>>>(cA, cB, cH0);
        scan3_kernel<<<(NCH * HID) / 256, blk, 0, stream>>>(slotA, slotB, cH0, slotC);
        // xh3 = silu(xb @ input_w[:HID].T) * xh2(slotB) -> slotA fp32 + P1 planes
        gemm_pipe<2, 128, 192><<<dim3(TT / 128, HID / 192), blk512, 0, stream>>>(
            xbP, xbN, iwlo, iwN, slotA, (float*)nullptr, slotB, P1, TH, TT, HID, DIMW);
        // k|v -> slotB [T][768]   (2-buf kernel, grid 192)
        gemm_mfma<0, 128, 128, 2, 2><<<dim3(TT / 128, (2 * DD) / 128), blk, 0, stream>>>(
            P1, TH, wkvp, kvN, slotB, (float*)nullptr, (const float*)nullptr,
            (_Float16*)nullptr, 0, TT, 2 * DD, HID);
        // segment attention -> membuf
        attn1_kernel<<<SSEG, blk, 0, stream>>>(slotB, qbuf, membuf);
        // xr = gelu(xh3)*h -> slotA fp32 in-place + P1 planes (fused split)
        gelu_mul_kernel<<<ewBlocks, blk, 0, stream>>>(slotA, slotC, P1, TH);
        // rq = xr @ rq_w.T -> slotB   (grid 96)
        gemm_mfma<0, 128, 128, 2, 2><<<dim3(TT / 128, DD / 128), blk, 0, stream>>>(
            P1, TH, rqwp, rqN, slotB, (float*)nullptr, (const float*)nullptr,
            (_Float16*)nullptr, 0, TT, DD, HID);
        // rk = mem @ rk_w.T ; rv = mem @ rv_w.T (tiny, fp32 path)
        gemm32<0, 64, 64><<<dim3(1, DD / 64), blk, 0, stream>>>(
            membuf, rk_w, rkbuf, (float*)nullptr, (const float*)nullptr, SSEG, DD, DD);
        gemm32<0, 64, 64><<<dim3(1, HID / 64), blk, 0, stream>>>(
            membuf, rv_w, rvbuf, (float*)nullptr, (const float*)nullptr, SSEG, HID, DD);
        // cross attention + gate -> fp16 planes in P1 directly
        attn2_kernel<<<TT, blk, 0, stream>>>(slotB, rkbuf, rvbuf, slotA, wg_w, P1, TH);
        // final projection -> d_out   (grid 256)
        gemm_mfma<0, 128, 128, 2, 2><<<dim3(TT / 128, DIMW / 128), blk, 0, stream>>>(
            P1, TH, owp, owN, outb, (float*)nullptr, (const float*)nullptr,
            (_Float16*)nullptr, 0, TT, DIMW, HID);
    }
}

// Round 7
// 2659.306 us; speedup vs baseline: 1.0420x; 1.0420x over previous
//
#include <hip/hip_runtime.h>
#include <math.h>

#define BB 4
#define TT 4096
#define DIMW 1024
#define HID 1536
#define HID2 3072
#define KC 4
#define SSEG 16
#define LSEG 256
#define DD 384
#define NCH 64          // scan chunks per batch
#define CHL 64          // tokens per chunk (NCH*CHL == TT)
#define TH  ((size_t)TT*(size_t)HID)   // elements in one T x HID slot
#define RKVN (DD + HID) // 1920 rows of merged rk|rv weight

typedef _Float16 h8 __attribute__((ext_vector_type(8)));
typedef float f4 __attribute__((ext_vector_type(4)));

#define RSCL 4.8828125e-4f   // 2^-11

// fp16 2-plane split with scaled residual: a ~= h0 + h1 * 2^-11.
__device__ __forceinline__ void hsplit(float a, _Float16& h0, _Float16& h1)
{
    _Float16 t = (_Float16)a;
    float tf = (float)t;
    if (fabsf(tf) < 6.103515625e-05f) { t = (_Float16)0.f; tf = 0.f; }
    h0 = t;
    h1 = (_Float16)((a - tf) * 2048.0f);
}

// async global->LDS, 16B per lane
__device__ __forceinline__ void gl_lds16(const _Float16* g, _Float16* l)
{
    __builtin_amdgcn_global_load_lds(
        (const __attribute__((address_space(1))) unsigned int*)g,
        (__attribute__((address_space(3))) unsigned int*)l,
        16, 0, 0);
}

// =====================================================================
// LDS-transpose split: fp32 [R][Kd] -> 2 fp16 planes kcm (weights + xb)
// =====================================================================
__global__ __launch_bounds__(256) void split2t(const float* __restrict__ src,
                                               _Float16* __restrict__ dst,
                                               int R, int Kd, size_t ps)
{
    __shared__ float tile[64][65];
    const int tid = threadIdx.x;
    const int bx = blockIdx.x;
    const int by = blockIdx.y;
    {
        const int lr = tid >> 2;
        const int lc = (tid & 3) * 16;
        const float* s = src + (size_t)(by * 64 + lr) * Kd + bx * 64 + lc;
#pragma unroll
        for (int e = 0; e < 16; e++) tile[lr][lc + e] = s[e];
    }
    __syncthreads();
    const int c = tid >> 5;
    const int r0 = tid & 31;
#pragma unroll
    for (int rr = 0; rr < 2; rr++) {
        const int r = r0 + rr * 32;
        h8 h0v, h1v;
#pragma unroll
        for (int e = 0; e < 8; e++) {
            _Float16 a0, a1;
            hsplit(tile[r][c * 8 + e], a0, a1);
            h0v[e] = a0; h1v[e] = a1;
        }
        const size_t didx = ((size_t)(bx * 8 + c) * R + by * 64 + r) * 8;
        *(h8*)(dst + didx) = h0v;
        *(h8*)(dst + ps + didx) = h1v;
    }
}

// generic 2-buffer row-concat: dst[0..n1) = s1, dst[n1..n1+n2) = s2
__global__ __launch_bounds__(256) void ccat2_kernel(const float* __restrict__ s1, int n1,
                                                    const float* __restrict__ s2, int n2,
                                                    float* __restrict__ dst)
{
    int i = blockIdx.x * 256 + threadIdx.x;
    if (i < n1) dst[i] = s1[i];
    else if (i < n1 + n2) dst[i] = s2[i - n1];
}

// =====================================================================
// 2-buffer fp16x2 MFMA GEMM (round-4 proven structure): C = A @ W^T
// Both operands 2 fp16 planes (scaled residual, kcm).  3 MFMA products,
// dual accumulators, stage-issued-before-compute, one barrier per K-step,
// global_load_lds staging, XCD block swizzle (grids %8==0).
// MODE 0: plain store
// MODE 2: C0 = silu(acc)*X, + fused fp16-plane split of C0 into OP
// MODE 3: gates+alpha: n<HID -> C0 = alpha(acc) (double math, uses SPB/GB);
//         n>=HID -> C1 = raw acc (bias added later)
// =====================================================================
template<int MODE, int TM, int TN, int WRN, int WCN>
__global__ __launch_bounds__(WRN * WCN * 64, 2) void gemm_mfma(
    const _Float16* __restrict__ Ap, size_t aps,
    const _Float16* __restrict__ Wp, size_t wps,
    float* __restrict__ C0, float* __restrict__ C1,
    const float* __restrict__ X,
    _Float16* __restrict__ OP, size_t ops,
    const double* __restrict__ SPB, const float* __restrict__ GB,
    int M, int Nout, int Kd)
{
    constexpr int NWAVE = WRN * WCN;
    constexpr int WTM = TM / WRN, WTN = TN / WCN;
    constexpr int MI = WTM / 16, NI = WTN / 16;
    constexpr int API = TM / 16;
    constexpr int BPI = TN / 16;
    constexpr int ATOT = 2 * API;
    constexpr int NISS = ATOT + 2 * BPI;
    static_assert(NISS % NWAVE == 0, "issue count must divide waves");
    static_assert(MI * NI <= 16, "DUAL only");

    __shared__ _Float16 Als[2][2][TM * 32];
    __shared__ _Float16 Bls[2][2][TN * 32];

    const int tid = threadIdx.x;
    const int lane = tid & 63;
    const int wv = tid >> 6;
    const int wr = wv / WCN, wc = wv % WCN;
    const int lr = lane & 15, lg = lane >> 4;

    int bx = blockIdx.x, by = blockIdx.y;
    {
        const int gx = gridDim.x;
        const int nwg = gx * gridDim.y;
        if ((nwg & 7) == 0) {
            int wg = by * gx + bx;
            wg = (wg & 7) * (nwg >> 3) + (wg >> 3);
            bx = wg % gx; by = wg / gx;
        }
    }
    const int m0 = bx * TM, n0 = by * TN;

    f4 acc1[MI][NI], acc2[MI][NI];
#pragma unroll
    for (int i = 0; i < MI; i++)
#pragma unroll
        for (int j = 0; j < NI; j++) {
            acc1[i][j] = (f4){0.f, 0.f, 0.f, 0.f};
            acc2[i][j] = (f4){0.f, 0.f, 0.f, 0.f};
        }

    auto stage = [&](int kq0, int buf) {
#pragma unroll
        for (int j = 0; j < NISS / NWAVE; j++) {
            const int i = j * NWAVE + wv;
            if (i < ATOT) {
                const int pl = i / API, s = i - pl * API;
                const int kc = (s * 64) / TM, r0 = (s * 64) % TM;
                gl_lds16(Ap + pl * aps + ((size_t)(kq0 + kc) * M + m0 + r0) * 8 + lane * 8,
                         &Als[buf][pl][(kc * TM + r0) * 8]);
            } else {
                const int jj = i - ATOT;
                const int pl = jj / BPI, s = jj - pl * BPI;
                const int kc = (s * 64) / TN, r0 = (s * 64) % TN;
                gl_lds16(Wp + pl * wps + ((size_t)(kq0 + kc) * Nout + n0 + r0) * 8 + lane * 8,
                         &Bls[buf][pl][(kc * TN + r0) * 8]);
            }
        }
    };

    stage(0, 0);
    __syncthreads();

    const int NS = Kd / 32;
    for (int t = 0; t < NS; t++) {
        const int buf = t & 1;
        if (t + 1 < NS) stage((t + 1) * 4, buf ^ 1);   // issue BEFORE compute

        h8 af0[MI], af1[MI];
#pragma unroll
        for (int mi = 0; mi < MI; mi++) {
            const int arow = wr * WTM + mi * 16 + lr;
            af0[mi] = *(const h8*)&Als[buf][0][(lg * TM + arow) * 8];
            af1[mi] = *(const h8*)&Als[buf][1][(lg * TM + arow) * 8];
        }
#pragma unroll
        for (int ni = 0; ni < NI; ni++) {
            const int brow = wc * WTN + ni * 16 + lr;
            h8 b0 = *(const h8*)&Bls[buf][0][(lg * TN + brow) * 8];
            h8 b1 = *(const h8*)&Bls[buf][1][(lg * TN + brow) * 8];
#pragma unroll
            for (int mi = 0; mi < MI; mi++) {
                acc1[mi][ni] = __builtin_amdgcn_mfma_f32_16x16x32_f16(af0[mi], b0, acc1[mi][ni], 0, 0, 0);
                acc2[mi][ni] = __builtin_amdgcn_mfma_f32_16x16x32_f16(af1[mi], b0, acc2[mi][ni], 0, 0, 0);
                acc2[mi][ni] = __builtin_amdgcn_mfma_f32_16x16x32_f16(af0[mi], b1, acc2[mi][ni], 0, 0, 0);
            }
        }
        __syncthreads();   // drains staged loads; next iter reads buf^1 safely
    }

#pragma unroll
    for (int mi = 0; mi < MI; mi++) {
#pragma unroll
        for (int ni = 0; ni < NI; ni++) {
#pragma unroll
            for (int r = 0; r < 4; r++) {
                const float v = acc1[mi][ni][r] + acc2[mi][ni][r] * RSCL;
                const int m = m0 + wr * WTM + mi * 16 + lg * 4 + r;
                const int n = n0 + wc * WTN + ni * 16 + lr;
                if constexpr (MODE == 3) {
                    if (n < HID) {
                        double f = (double)v + (double)GB[n];
                        double sigf = 1.0 / (1.0 + exp(-f));
                        C0[(size_t)m * HID + n] = (float)exp(-8.0 * SPB[n] * sigf);
                    } else {
                        C1[(size_t)m * HID + (n - HID)] = v;
                    }
                } else if constexpr (MODE == 2) {
                    float g = v;
                    float fv = (g / (1.0f + expf(-g))) * X[(size_t)m * Nout + n];
                    C0[(size_t)m * Nout + n] = fv;
                    _Float16 a0, a1;
                    hsplit(fv, a0, a1);
                    const size_t didx = ((size_t)(n >> 3) * M + m) * 8 + (n & 7);
                    OP[didx] = a0;
                    OP[ops + didx] = a1;
                } else {
                    C0[(size_t)m * Nout + n] = v;
                }
            }
        }
    }
}

// =====================================================================
// fp32 VALU GEMM kept only for tiny M=16 matmuls (q, rkv)
// =====================================================================
template<int TM, int TN>
__global__ __launch_bounds__(256) void gemm32(const float* __restrict__ A,
                                              const float* __restrict__ W,
                                              float* __restrict__ C0,
                                              int M, int Nout, int Kd)
{
    constexpr int GM = TM / 64;
    constexpr int GN = TN / 64;
    constexpr int AF4 = TM * 4;
    constexpr int WF4 = TN * 4;
    constexpr int ALOOP = (AF4 + 255) / 256;
    constexpr int WLOOP = (WF4 + 255) / 256;

    __shared__ float As[16][TM];
    __shared__ float Bs[16][TN];

    const int tid = threadIdx.x;
    const int m0 = blockIdx.x * TM;
    const int n0 = blockIdx.y * TN;
    const int tx = tid & 15, ty = tid >> 4;

    float acc[GM * 4][GN * 4];
#pragma unroll
    for (int i = 0; i < GM * 4; i++)
#pragma unroll
        for (int j = 0; j < GN * 4; j++) acc[i][j] = 0.0f;

    float4 aReg[ALOOP], wReg[WLOOP];

    auto issueLoads = [&](int k0) {
#pragma unroll
        for (int u = 0; u < ALOOP; u++) {
            const int idx = tid + u * 256;
            float4 v = make_float4(0.f, 0.f, 0.f, 0.f);
            if (idx < AF4) {
                const int row = idx >> 2, kq = (idx & 3) * 4;
                const long ar = (long)(m0 + row);
                if (ar < M) v = *(const float4*)(A + ar * (long)Kd + (k0 + kq));
            }
            aReg[u] = v;
        }
#pragma unroll
        for (int u = 0; u < WLOOP; u++) {
            const int idx = tid + u * 256;
            float4 v = make_float4(0.f, 0.f, 0.f, 0.f);
            if (idx < WF4) {
                const int row = idx >> 2, kq = (idx & 3) * 4;
                const long wr = (long)(n0 + row);
                if (wr < Nout) v = *(const float4*)(W + wr * (long)Kd + (k0 + kq));
            }
            wReg[u] = v;
        }
    };
    auto writeLDS = [&]() {
#pragma unroll
        for (int u = 0; u < ALOOP; u++) {
            const int idx = tid + u * 256;
            if (idx < AF4) {
                const int row = idx >> 2, kq = (idx & 3) * 4;
                As[kq + 0][row] = aReg[u].x;
                As[kq + 1][row] = aReg[u].y;
                As[kq + 2][row] = aReg[u].z;
                As[kq + 3][row] = aReg[u].w;
            }
        }
#pragma unroll
        for (int u = 0; u < WLOOP; u++) {
            const int idx = tid + u * 256;
            if (idx < WF4) {
                const int row = idx >> 2, kq = (idx & 3) * 4;
                Bs[kq + 0][row] = wReg[u].x;
                Bs[kq + 1][row] = wReg[u].y;
                Bs[kq + 2][row] = wReg[u].z;
                Bs[kq + 3][row] = wReg[u].w;
            }
        }
    };

    issueLoads(0);
    writeLDS();
    __syncthreads();

    const int NT = Kd / 16;
    for (int t = 0; t < NT; t++) {
        if (t + 1 < NT) issueLoads((t + 1) * 16);
#pragma unroll
        for (int k = 0; k < 16; k++) {
            float a[GM * 4], b[GN * 4];
#pragma unroll
            for (int g = 0; g < GM; g++) {
                const float4 t4 = *(const float4*)&As[k][g * 64 + ty * 4];
                a[g * 4 + 0] = t4.x; a[g * 4 + 1] = t4.y;
                a[g * 4 + 2] = t4.z; a[g * 4 + 3] = t4.w;
            }
#pragma unroll
            for (int g = 0; g < GN; g++) {
                const float4 t4 = *(const float4*)&Bs[k][g * 64 + tx * 4];
                b[g * 4 + 0] = t4.x; b[g * 4 + 1] = t4.y;
                b[g * 4 + 2] = t4.z; b[g * 4 + 3] = t4.w;
            }
#pragma unroll
            for (int i = 0; i < GM * 4; i++)
#pragma unroll
                for (int j = 0; j < GN * 4; j++) acc[i][j] += a[i] * b[j];
        }
        __syncthreads();
        if (t + 1 < NT) {
            writeLDS();
            __syncthreads();
        }
    }

#pragma unroll
    for (int i = 0; i < GM * 4; i++) {
        const int m = m0 + (i >> 2) * 64 + ty * 4 + (i & 3);
        if (m >= M) continue;
#pragma unroll
        for (int j = 0; j < GN * 4; j++) {
            const int n = n0 + (j >> 2) * 64 + tx * 4 + (j & 3);
            if (n >= Nout) continue;
            C0[(long)m * Nout + n] = acc[i][j];
        }
    }
}

// softplus(forget_base) per channel (once) -- double (feeds sensitive alpha path)
__global__ __launch_bounds__(256) void spb_kernel(const float* __restrict__ fb,
                                                  double* __restrict__ spb)
{
    int h = blockIdx.x * 256 + threadIdx.x;
    if (h < HID) {
        double xv = (double)fb[h];
        spb[h] = log1p(exp(xv));
    }
}

// causal depthwise conv (one batch), fp32 math, fused fp16-plane split
__global__ __launch_bounds__(256) void conv_kernel(const float* __restrict__ xin,
                                                   const float* __restrict__ cw,
                                                   const float* __restrict__ cb,
                                                   float* __restrict__ outp,
                                                   _Float16* __restrict__ outP,
                                                   size_t ps)
{
    size_t i = (size_t)blockIdx.x * 256 + threadIdx.x;
    if (i >= TH) return;
    int h = (int)(i % HID);
    int t = (int)(i / HID);
    float acc = cb[h];
#pragma unroll
    for (int j = 0; j < KC; j++) {
        int tt = t - (KC - 1) + j;
        if (tt >= 0) acc = fmaf(cw[h * KC + j], xin[(size_t)tt * HID + h], acc);
    }
    outp[i] = acc;
    _Float16 a0, a1;
    hsplit(acc, a0, a1);
    const size_t didx = ((size_t)(h >> 3) * TT + t) * 8 + (h & 7);
    outP[didx] = a0;
    outP[ps + didx] = a1;
}

// xh2 from alpha (already computed in gates epilogue) + raw inp + xh1
__global__ __launch_bounds__(256) void xh2_kernel(const float* __restrict__ alpha,
                                                  float* __restrict__ ip,
                                                  const float* __restrict__ xh1,
                                                  const float* __restrict__ gb)
{
    size_t i = (size_t)blockIdx.x * 256 + threadIdx.x;
    if (i >= TH) return;
    int h = (int)(i % HID);
    float a = alpha[i];
    float g2 = ip[i] + gb[HID + h];
    float s2 = sqrtf(1.0f - a * a + 1e-6f);
    float sigi = 1.0f / (1.0f + expf(-g2));
    ip[i] = s2 * sigi * xh1[i];
}

// scan pass1 (double accumulation)
__global__ __launch_bounds__(256) void scan1_kernel(const float* __restrict__ alpha,
                                                    const float* __restrict__ xh2,
                                                    double* __restrict__ cA,
                                                    double* __restrict__ cB)
{
    int idx = blockIdx.x * 256 + threadIdx.x;
    if (idx >= NCH * HID) return;
    int h = idx % HID;
    int c = idx / HID;
    size_t base = (size_t)c * CHL * HID + h;
    double aP = 1.0, bV = 0.0;
    for (int i = 0; i < CHL; i++) {
        double a  = (double)alpha[base + (size_t)i * HID];
        double xv = (double)xh2 [base + (size_t)i * HID];
        bV = a * bV + xv;
        aP *= a;
    }
    size_t o = (size_t)c * HID + h;
    cA[o] = aP;
    cB[o] = bV;
}

// scan pass2
__global__ __launch_bounds__(256) void scan2_kernel(const double* __restrict__ cA,
                                                    const double* __restrict__ cB,
                                                    double* __restrict__ cH0)
{
    int h = blockIdx.x * 256 + threadIdx.x;
    if (h >= HID) return;
    double carry = 0.0;
    for (int c = 0; c < NCH; c++) {
        size_t o = (size_t)c * HID + h;
        cH0[o] = carry;
        carry = cA[o] * carry + cB[o];
    }
}

// scan pass3
__global__ __launch_bounds__(256) void scan3_kernel(const float* __restrict__ alpha,
                                                    const float* __restrict__ xh2,
                                                    const double* __restrict__ cH0,
                                                    float* __restrict__ hout)
{
    int idx = blockIdx.x * 256 + threadIdx.x;
    if (idx >= NCH * HID) return;
    int h = idx % HID;
    int c = idx / HID;
    size_t base = (size_t)c * CHL * HID + h;
    double hv = cH0[(size_t)c * HID + h];
    for (int i = 0; i < CHL; i++) {
        double a  = (double)alpha[base + (size_t)i * HID];
        double xv = (double)xh2 [base + (size_t)i * HID];
        hv = a * hv + xv;
        hout[base + (size_t)i * HID] = (float)hv;
    }
}

// xr = gelu_exact(xh3)*h, fp32 math, fused fp16-plane split
__global__ __launch_bounds__(256) void gelu_mul_kernel(float* __restrict__ xh3,
                                                       const float* __restrict__ hbuf,
                                                       _Float16* __restrict__ outP,
                                                       size_t ps)
{
    size_t i = (size_t)blockIdx.x * 256 + threadIdx.x;
    if (i >= TH) return;
    int h = (int)(i % HID);
    int t = (int)(i / HID);
    float x3 = xh3[i];
    float ge = 0.5f * x3 * (1.0f + erff(x3 * 0.70710678f));
    float fv = ge * hbuf[i];
    xh3[i] = fv;
    _Float16 a0, a1;
    hsplit(fv, a0, a1);
    const size_t didx = ((size_t)(h >> 3) * TT + t) * 8 + (h & 7);
    outP[didx] = a0;
    outP[ps + didx] = a1;
}

// attention 1: kv is [T][2*DD], cols [0,DD)=k, [DD,2DD)=v
__global__ __launch_bounds__(256) void attn1_kernel(const float* __restrict__ kv,
                                                    const float* __restrict__ qbuf,
                                                    float* __restrict__ mem)
{
    const int s = blockIdx.x;
    const int l = threadIdx.x;
    const size_t row = (size_t)s * LSEG + l;
    const float* kr = kv + row * (2 * DD);
    const float* qs = qbuf + (size_t)s * DD;
    double acc = 0.0;
    for (int d = 0; d < DD; d++) acc += (double)qs[d] * (double)kr[d];
    double qk = acc / sqrt((double)DD);
    __shared__ double r1[256];
    __shared__ double sw[256];
    r1[l] = qk; __syncthreads();
    for (int off = 128; off > 0; off >>= 1) {
        if (l < off) r1[l] = fmax(r1[l], r1[l + off]);
        __syncthreads();
    }
    double m = r1[0]; __syncthreads();
    double e = exp(qk - m);
    r1[l] = e; __syncthreads();
    for (int off = 128; off > 0; off >>= 1) {
        if (l < off) r1[l] += r1[l + off];
        __syncthreads();
    }
    double denom = r1[0];
    sw[l] = e / denom; __syncthreads();
    const size_t vbase = (size_t)s * LSEG * (2 * DD) + DD;
    for (int d = l; d < DD; d += 256) {
        double a2 = 0.0;
        for (int ll = 0; ll < LSEG; ll++)
            a2 += sw[ll] * (double)kv[vbase + (size_t)ll * (2 * DD) + d];
        mem[(size_t)s * DD + d] = (float)a2;
    }
}

// attention 2 + output gate; rkv combined [16][1920] (rk cols 0..383, rv 384..1919)
__global__ __launch_bounds__(256) void attn2_kernel(const float* __restrict__ rq,
                                                    const float* __restrict__ rkv,
                                                    const float* __restrict__ xr,
                                                    const float* __restrict__ wg,
                                                    _Float16* __restrict__ outP,
                                                    size_t ps)
{
    const int t = blockIdx.x;
    const int sigma = t >> 8;
    const int tid = threadIdx.x;
    __shared__ double sqk[16];
    __shared__ double red[256];
    __shared__ double sw[16];
    __shared__ double sgate;

    const float* rqn = rq + (size_t)t * DD;
    {
        int s = tid >> 4, j = tid & 15;
        const float* rks = rkv + (size_t)s * RKVN;
        double part = 0.0;
        for (int d = j; d < DD; d += 16) part += (double)rqn[d] * (double)rks[d];
#pragma unroll
        for (int off = 8; off > 0; off >>= 1) part += __shfl_down(part, off, 16);
        if (j == 0) sqk[s] = part;
    }
    double gp = 0.0;
    const float* xrn = xr + (size_t)t * HID;
    for (int hh = tid; hh < HID; hh += 256) gp += (double)xrn[hh] * (double)wg[hh];
    red[tid] = gp; __syncthreads();
    for (int off = 128; off > 0; off >>= 1) {
        if (tid < off) red[tid] += red[tid + off];
        __syncthreads();
    }
    if (tid == 0) {
        const double inv = 1.0 / sqrt((double)DD);
        double m = -1e300;
        for (int ss = sigma; ss < 16; ss++) {
            double v = sqk[ss] * inv;
            sqk[ss] = v;
            if (v > m) m = v;
        }
        double sum = 0.0;
        for (int ss = sigma; ss < 16; ss++) {
            double e = exp(sqk[ss] - m);
            sw[ss] = e;
            sum += e;
        }
        double isum = 1.0 / sum;
        for (int ss = 0; ss < sigma; ss++) sw[ss] = 0.0;
        for (int ss = sigma; ss < 16; ss++) sw[ss] *= isum;
        sgate = 1.0 / (1.0 + exp(-red[0]));
    }
    __syncthreads();
    const double gte = sgate;
    for (int c = tid; c < HID / 8; c += 256) {
        double accv[8] = {0, 0, 0, 0, 0, 0, 0, 0};
        for (int ss = sigma; ss < 16; ss++) {
            const float* rvp = rkv + (size_t)ss * RKVN + DD + c * 8;
            double w = sw[ss];
#pragma unroll
            for (int e = 0; e < 8; e++) accv[e] += w * (double)rvp[e];
        }
        h8 h0v, h1v;
#pragma unroll
        for (int e = 0; e < 8; e++) {
            _Float16 a0, a1;
            hsplit((float)(gte * accv[e]), a0, a1);
            h0v[e] = a0; h1v[e] = a1;
        }
        const size_t didx = ((size_t)c * TT + t) * 8;
        *(h8*)(outP + didx) = h0v;
        *(h8*)(outP + ps + didx) = h1v;
    }
}

extern "C" void kernel_launch(void* const* d_in, const int* in_sizes, int n_in,
                              void* d_out, int out_size, void* d_ws, size_t ws_size,
                              hipStream_t stream)
{
    const float* x            = (const float*)d_in[0];
    const float* input_w      = (const float*)d_in[1];
    const float* conv_w       = (const float*)d_in[2];
    const float* conv_b       = (const float*)d_in[3];
    const float* gates_w      = (const float*)d_in[4];
    const float* gates_b      = (const float*)d_in[5];
    const float* forget_base  = (const float*)d_in[6];
    const float* output_w     = (const float*)d_in[7];
    const float* memory_slots = (const float*)d_in[8];
    const float* wq_w         = (const float*)d_in[9];
    const float* wk_w         = (const float*)d_in[10];
    const float* wv_w         = (const float*)d_in[11];
    const float* wg_w         = (const float*)d_in[12];
    const float* rq_w         = (const float*)d_in[13];
    const float* rk_w         = (const float*)d_in[14];
    const float* rv_w         = (const float*)d_in[15];
    float* out = (float*)d_out;

    // ---- workspace layout (~170 MB) ----
    double* spb  = (double*)d_ws;                     // HID
    double* cA   = spb + HID;                         // NCH*HID
    double* cB   = cA + (size_t)NCH * HID;
    double* cH0  = cB + (size_t)NCH * HID;
    float* slotA = (float*)(cH0 + (size_t)NCH * HID); // TH floats each
    float* slotB = slotA + TH;
    float* slotC = slotB + TH;
    float* qbuf   = slotC + TH;                       // 16*384
    float* membuf = qbuf + (size_t)SSEG * DD;         // 16*384
    float* rkvw   = membuf + (size_t)SSEG * DD;       // 1920*384
    float* rkvbuf = rkvw + (size_t)RKVN * DD;         // 16*1920

    _Float16* base_h = (_Float16*)(rkvbuf + (size_t)SSEG * RKVN);
    const size_t iwN  = (size_t)HID * DIMW;           // per-half input_w
    const size_t gwN  = (size_t)HID2 * HID;
    const size_t kvN  = (size_t)(2 * DD) * HID;
    const size_t rqN  = (size_t)DD * HID;
    const size_t owN  = (size_t)DIMW * HID;
    const size_t xbN  = (size_t)TT * DIMW;
    _Float16* iwlo = base_h;                          // 2*iwN
    _Float16* iwhi = iwlo + 2 * iwN;
    _Float16* gwp  = iwhi + 2 * iwN;
    _Float16* wkvp = gwp  + 2 * gwN;
    _Float16* rqwp = wkvp + 2 * kvN;
    _Float16* owp  = rqwp + 2 * rqN;
    _Float16* xbP  = owp  + 2 * owN;                  // 2*xbN
    _Float16* P1   = xbP  + 2 * xbN;                  // 2*TH

    dim3 blk(256);
    const int ewBlocks = (int)(TH / 256);

    // ---- one-time: softplus, weight splits/concats, q projection ----
    spb_kernel<<<(HID + 255) / 256, blk, 0, stream>>>(forget_base, spb);
    // wkv fp32 concat into slotA, then split
    ccat2_kernel<<<(2 * DD * HID + 255) / 256, blk, 0, stream>>>(
        wk_w, DD * HID, wv_w, DD * HID, slotA);
    // rkv fp32 concat (rk_w 384x384 rows | rv_w 1536x384 rows)
    ccat2_kernel<<<(RKVN * DD + 255) / 256, blk, 0, stream>>>(
        rk_w, DD * DD, rv_w, HID * DD, rkvw);
    split2t<<<dim3(DIMW / 64, HID / 64), blk, 0, stream>>>(input_w, iwlo, HID, DIMW, iwN);
    split2t<<<dim3(DIMW / 64, HID / 64), blk, 0, stream>>>(input_w + (size_t)HID * DIMW,
                                                           iwhi, HID, DIMW, iwN);
    split2t<<<dim3(HID / 64, HID2 / 64), blk, 0, stream>>>(gates_w, gwp, HID2, HID, gwN);
    split2t<<<dim3(HID / 64, (2 * DD) / 64), blk, 0, stream>>>(slotA, wkvp, 2 * DD, HID, kvN);
    split2t<<<dim3(HID / 64, DD / 64), blk, 0, stream>>>(rq_w, rqwp, DD, HID, rqN);
    split2t<<<dim3(HID / 64, DIMW / 64), blk, 0, stream>>>(output_w, owp, DIMW, HID, owN);
    gemm32<64, 64><<<dim3(1, DD / 64), blk, 0, stream>>>(
        memory_slots, wq_w, qbuf, SSEG, DD, DD);

    for (int b = 0; b < BB; b++) {
        const float* xb   = x   + (size_t)b * TT * DIMW;
        float*       outb = out + (size_t)b * TT * DIMW;

        // split xb once (shared by xh0 GEMM and silu GEMM)
        split2t<<<dim3(DIMW / 64, TT / 64), blk, 0, stream>>>(xb, xbP, TT, DIMW, xbN);
        // xh0 = xb @ input_w[HID:,:].T -> slotB   (grid 384)
        gemm_mfma<0, 128, 128, 2, 2><<<dim3(TT / 128, HID / 128), blk, 0, stream>>>(
            xbP, xbN, iwhi, iwN, slotB, (float*)nullptr, (const float*)nullptr,
            (_Float16*)nullptr, 0, (const double*)nullptr, (const float*)nullptr,
            TT, HID, DIMW);
        // xh1 = causal conv(xh0) -> slotC fp32 + P1 planes (fused split)
        conv_kernel<<<ewBlocks, blk, 0, stream>>>(slotB, conv_w, conv_b, slotC, P1, TH);
        // gates: forget-half -> alpha(slotA) in epilogue; inp raw -> slotB (grid 768)
        gemm_mfma<3, 128, 128, 2, 2><<<dim3(TT / 128, HID2 / 128), blk, 0, stream>>>(
            P1, TH, gwp, gwN, slotA, slotB, (const float*)nullptr,
            (_Float16*)nullptr, 0, spb, gates_b, TT, HID2, HID);
        // xh2(slotB) from alpha(slotA), raw inp, xh1(slotC)
        xh2_kernel<<<ewBlocks, blk, 0, stream>>>(slotA, slotB, slotC, gates_b);
        // scan -> h(slotC)
        scan1_kernel<<<(NCH * HID) / 256, blk, 0, stream>>>(slotA, slotB, cA, cB);
        scan2_kernel<<<(HID + 255) / 256, blk, 0, stream>>>(cA, cB, cH0);
        scan3_kernel<<<(NCH * HID) / 256, blk, 0, stream>>>(slotA, slotB, cH0, slotC);
        // xh3 = silu(xb @ input_w[:HID].T) * xh2(slotB) -> slotA fp32 + P1 planes
        gemm_mfma<2, 128, 128, 2, 2><<<dim3(TT / 128, HID / 128), blk, 0, stream>>>(
            xbP, xbN, iwlo, iwN, slotA, (float*)nullptr, slotB, P1, TH,
            (const double*)nullptr, (const float*)nullptr, TT, HID, DIMW);
        // k|v -> slotB [T][768]   (grid 192)
        gemm_mfma<0, 128, 128, 2, 2><<<dim3(TT / 128, (2 * DD) / 128), blk, 0, stream>>>(
            P1, TH, wkvp, kvN, slotB, (float*)nullptr, (const float*)nullptr,
            (_Float16*)nullptr, 0, (const double*)nullptr, (const float*)nullptr,
            TT, 2 * DD, HID);
        // segment attention -> membuf
        attn1_kernel<<<SSEG, blk, 0, stream>>>(slotB, qbuf, membuf);
        // xr = gelu(xh3)*h -> slotA fp32 in-place + P1 planes (fused split)
        gelu_mul_kernel<<<ewBlocks, blk, 0, stream>>>(slotA, slotC, P1, TH);
        // rq = xr @ rq_w.T -> slotB   (64x128 tile, grid 192)
        gemm_mfma<0, 64, 128, 2, 2><<<dim3(TT / 64, DD / 128), blk, 0, stream>>>(
            P1, TH, rqwp, rqN, slotB, (float*)nullptr, (const float*)nullptr,
            (_Float16*)nullptr, 0, (const double*)nullptr, (const float*)nullptr,
            TT, DD, HID);
        // rk|rv = mem @ rkv_w.T (merged, grid 30)
        gemm32<64, 64><<<dim3(1, (RKVN + 63) / 64), blk, 0, stream>>>(
            membuf, rkvw, rkvbuf, SSEG, RKVN, DD);
        // cross attention + gate -> fp16 planes in P1 directly
        attn2_kernel<<<TT, blk, 0, stream>>>(slotB, rkvbuf, slotA, wg_w, P1, TH);
        // final projection -> d_out   (grid 256)
        gemm_mfma<0, 128, 128, 2, 2><<<dim3(TT / 128, DIMW / 128), blk, 0, stream>>>(
            P1, TH, owp, owN, outb, (float*)nullptr, (const float*)nullptr,
            (_Float16*)nullptr, 0, (const double*)nullptr, (const float*)nullptr,
            TT, DIMW, HID);
    }
}

// Round 8
// 2473.905 us; speedup vs baseline: 1.1201x; 1.0749x over previous
//
#include <hip/hip_runtime.h>
#include <math.h>

#define BB 4
#define TT 4096
#define DIMW 1024
#define HID 1536
#define HID2 3072
#define KC 4
#define SSEG 16
#define LSEG 256
#define DD 384
#define NCH 64          // scan chunks per batch
#define CHL 64          // tokens per chunk (NCH*CHL == TT)
#define TH  ((size_t)TT*(size_t)HID)   // elements in one T x HID slot
#define RKVN (DD + HID) // 1920 rows of merged rk|rv weight

typedef _Float16 h8 __attribute__((ext_vector_type(8)));
typedef float f4 __attribute__((ext_vector_type(4)));

#define RSCL 4.8828125e-4f   // 2^-11

// fp16 2-plane split with scaled residual: a ~= h0 + h1 * 2^-11.
__device__ __forceinline__ void hsplit(float a, _Float16& h0, _Float16& h1)
{
    _Float16 t = (_Float16)a;
    float tf = (float)t;
    if (fabsf(tf) < 6.103515625e-05f) { t = (_Float16)0.f; tf = 0.f; }
    h0 = t;
    h1 = (_Float16)((a - tf) * 2048.0f);
}

// async global->LDS, 16B per lane
__device__ __forceinline__ void gl_lds16(const _Float16* g, _Float16* l)
{
    __builtin_amdgcn_global_load_lds(
        (const __attribute__((address_space(1))) unsigned int*)g,
        (__attribute__((address_space(3))) unsigned int*)l,
        16, 0, 0);
}

// =====================================================================
// LDS-transpose split: fp32 [R][Kd] -> 2 fp16 planes kcm (weights + xb)
// =====================================================================
__global__ __launch_bounds__(256) void split2t(const float* __restrict__ src,
                                               _Float16* __restrict__ dst,
                                               int R, int Kd, size_t ps)
{
    __shared__ float tile[64][65];
    const int tid = threadIdx.x;
    const int bx = blockIdx.x;
    const int by = blockIdx.y;
    {
        const int lr = tid >> 2;
        const int lc = (tid & 3) * 16;
        const float* s = src + (size_t)(by * 64 + lr) * Kd + bx * 64 + lc;
#pragma unroll
        for (int e = 0; e < 16; e++) tile[lr][lc + e] = s[e];
    }
    __syncthreads();
    const int c = tid >> 5;
    const int r0 = tid & 31;
#pragma unroll
    for (int rr = 0; rr < 2; rr++) {
        const int r = r0 + rr * 32;
        h8 h0v, h1v;
#pragma unroll
        for (int e = 0; e < 8; e++) {
            _Float16 a0, a1;
            hsplit(tile[r][c * 8 + e], a0, a1);
            h0v[e] = a0; h1v[e] = a1;
        }
        const size_t didx = ((size_t)(bx * 8 + c) * R + by * 64 + r) * 8;
        *(h8*)(dst + didx) = h0v;
        *(h8*)(dst + ps + didx) = h1v;
    }
}

// generic 2-buffer row-concat: dst[0..n1) = s1, dst[n1..n1+n2) = s2
__global__ __launch_bounds__(256) void ccat2_kernel(const float* __restrict__ s1, int n1,
                                                    const float* __restrict__ s2, int n2,
                                                    float* __restrict__ dst)
{
    int i = blockIdx.x * 256 + threadIdx.x;
    if (i < n1) dst[i] = s1[i];
    else if (i < n1 + n2) dst[i] = s2[i - n1];
}

// =====================================================================
// 2-buffer fp16x2 MFMA GEMM, 8 waves (2x4): C = A @ W^T
// Both operands 2 fp16 planes (scaled residual, kcm).  3 MFMA products,
// dual accumulators, stage-issued-before-compute, one barrier per K-step,
// global_load_lds staging, XCD block swizzle (grids %8==0).
// 512 threads, 64KB LDS -> 2 blocks/CU = 16 waves/CU (4/SIMD).
// MODE 0: plain store (row stride Nout)
// MODE 1: split cols at HID -> C0/C1 (both stride HID)
// MODE 2: C0 = silu(acc)*X, + fused fp16-plane split of C0 into OP
// =====================================================================
template<int MODE, int TM, int TN>
__global__ __launch_bounds__(512, 4) void gemm_mfma(
    const _Float16* __restrict__ Ap, size_t aps,
    const _Float16* __restrict__ Wp, size_t wps,
    float* __restrict__ C0, float* __restrict__ C1,
    const float* __restrict__ X,
    _Float16* __restrict__ OP, size_t ops,
    int M, int Nout, int Kd)
{
    constexpr int WTM = TM / 2, WTN = TN / 4;
    constexpr int MI = WTM / 16, NI = WTN / 16;
    static_assert(MI * NI <= 16, "DUAL only");
    constexpr int API = TM / 16;
    constexpr int BPI = TN / 16;
    constexpr int ATOT = 2 * API;
    constexpr int NISS = ATOT + 2 * BPI;
    static_assert(NISS % 8 == 0, "issue count must divide 8 waves");
    constexpr int PW = NISS / 8;

    __shared__ _Float16 Als[2][2][TM * 32];
    __shared__ _Float16 Bls[2][2][TN * 32];

    const int tid = threadIdx.x;
    const int lane = tid & 63;
    const int wv = tid >> 6;
    const int wr = wv >> 2, wc = wv & 3;
    const int lr = lane & 15, lg = lane >> 4;

    int bx = blockIdx.x, by = blockIdx.y;
    {
        const int gx = gridDim.x;
        const int nwg = gx * gridDim.y;
        if ((nwg & 7) == 0) {
            int wg = by * gx + bx;
            wg = (wg & 7) * (nwg >> 3) + (wg >> 3);
            bx = wg % gx; by = wg / gx;
        }
    }
    const int m0 = bx * TM, n0 = by * TN;

    f4 acc1[MI][NI], acc2[MI][NI];
#pragma unroll
    for (int i = 0; i < MI; i++)
#pragma unroll
        for (int j = 0; j < NI; j++) {
            acc1[i][j] = (f4){0.f, 0.f, 0.f, 0.f};
            acc2[i][j] = (f4){0.f, 0.f, 0.f, 0.f};
        }

    auto stage = [&](int kq0, int buf) {
#pragma unroll
        for (int j = 0; j < PW; j++) {
            const int i = j * 8 + wv;
            if (i < ATOT) {
                const int pl = i / API, s = i - pl * API;
                const int kc = (s * 64) / TM, r0 = (s * 64) % TM;
                gl_lds16(Ap + pl * aps + ((size_t)(kq0 + kc) * M + m0 + r0) * 8 + lane * 8,
                         &Als[buf][pl][(kc * TM + r0) * 8]);
            } else {
                const int jj = i - ATOT;
                const int pl = jj / BPI, s = jj - pl * BPI;
                const int kc = (s * 64) / TN, r0 = (s * 64) % TN;
                gl_lds16(Wp + pl * wps + ((size_t)(kq0 + kc) * Nout + n0 + r0) * 8 + lane * 8,
                         &Bls[buf][pl][(kc * TN + r0) * 8]);
            }
        }
    };

    stage(0, 0);
    __syncthreads();

    const int NS = Kd / 32;
    for (int t = 0; t < NS; t++) {
        const int buf = t & 1;
        if (t + 1 < NS) stage((t + 1) * 4, buf ^ 1);   // issue BEFORE compute

        h8 af0[MI], af1[MI];
#pragma unroll
        for (int mi = 0; mi < MI; mi++) {
            const int arow = wr * WTM + mi * 16 + lr;
            af0[mi] = *(const h8*)&Als[buf][0][(lg * TM + arow) * 8];
            af1[mi] = *(const h8*)&Als[buf][1][(lg * TM + arow) * 8];
        }
#pragma unroll
        for (int ni = 0; ni < NI; ni++) {
            const int brow = wc * WTN + ni * 16 + lr;
            h8 b0 = *(const h8*)&Bls[buf][0][(lg * TN + brow) * 8];
            h8 b1 = *(const h8*)&Bls[buf][1][(lg * TN + brow) * 8];
#pragma unroll
            for (int mi = 0; mi < MI; mi++) {
                acc1[mi][ni] = __builtin_amdgcn_mfma_f32_16x16x32_f16(af0[mi], b0, acc1[mi][ni], 0, 0, 0);
                acc2[mi][ni] = __builtin_amdgcn_mfma_f32_16x16x32_f16(af1[mi], b0, acc2[mi][ni], 0, 0, 0);
                acc2[mi][ni] = __builtin_amdgcn_mfma_f32_16x16x32_f16(af0[mi], b1, acc2[mi][ni], 0, 0, 0);
            }
        }
        __syncthreads();   // drains staged loads; next iter reads buf^1 safely
    }

#pragma unroll
    for (int mi = 0; mi < MI; mi++) {
#pragma unroll
        for (int ni = 0; ni < NI; ni++) {
#pragma unroll
            for (int r = 0; r < 4; r++) {
                const float v = acc1[mi][ni][r] + acc2[mi][ni][r] * RSCL;
                const int m = m0 + wr * WTM + mi * 16 + lg * 4 + r;
                const int n = n0 + wc * WTN + ni * 16 + lr;
                if constexpr (MODE == 1) {
                    if (n < HID) C0[(size_t)m * HID + n] = v;
                    else         C1[(size_t)m * HID + (n - HID)] = v;
                } else if constexpr (MODE == 2) {
                    float g = v;
                    float fv = (g / (1.0f + expf(-g))) * X[(size_t)m * Nout + n];
                    C0[(size_t)m * Nout + n] = fv;
                    _Float16 a0, a1;
                    hsplit(fv, a0, a1);
                    const size_t didx = ((size_t)(n >> 3) * M + m) * 8 + (n & 7);
                    OP[didx] = a0;
                    OP[ops + didx] = a1;
                } else {
                    C0[(size_t)m * Nout + n] = v;
                }
            }
        }
    }
}

// =====================================================================
// fp32 VALU GEMM kept only for tiny M=16 matmuls (q, rkv)
// =====================================================================
template<int TM, int TN>
__global__ __launch_bounds__(256) void gemm32(const float* __restrict__ A,
                                              const float* __restrict__ W,
                                              float* __restrict__ C0,
                                              int M, int Nout, int Kd)
{
    constexpr int GM = TM / 64;
    constexpr int GN = TN / 64;
    constexpr int AF4 = TM * 4;
    constexpr int WF4 = TN * 4;
    constexpr int ALOOP = (AF4 + 255) / 256;
    constexpr int WLOOP = (WF4 + 255) / 256;

    __shared__ float As[16][TM];
    __shared__ float Bs[16][TN];

    const int tid = threadIdx.x;
    const int m0 = blockIdx.x * TM;
    const int n0 = blockIdx.y * TN;
    const int tx = tid & 15, ty = tid >> 4;

    float acc[GM * 4][GN * 4];
#pragma unroll
    for (int i = 0; i < GM * 4; i++)
#pragma unroll
        for (int j = 0; j < GN * 4; j++) acc[i][j] = 0.0f;

    float4 aReg[ALOOP], wReg[WLOOP];

    auto issueLoads = [&](int k0) {
#pragma unroll
        for (int u = 0; u < ALOOP; u++) {
            const int idx = tid + u * 256;
            float4 v = make_float4(0.f, 0.f, 0.f, 0.f);
            if (idx < AF4) {
                const int row = idx >> 2, kq = (idx & 3) * 4;
                const long ar = (long)(m0 + row);
                if (ar < M) v = *(const float4*)(A + ar * (long)Kd + (k0 + kq));
            }
            aReg[u] = v;
        }
#pragma unroll
        for (int u = 0; u < WLOOP; u++) {
            const int idx = tid + u * 256;
            float4 v = make_float4(0.f, 0.f, 0.f, 0.f);
            if (idx < WF4) {
                const int row = idx >> 2, kq = (idx & 3) * 4;
                const long wr = (long)(n0 + row);
                if (wr < Nout) v = *(const float4*)(W + wr * (long)Kd + (k0 + kq));
            }
            wReg[u] = v;
        }
    };
    auto writeLDS = [&]() {
#pragma unroll
        for (int u = 0; u < ALOOP; u++) {
            const int idx = tid + u * 256;
            if (idx < AF4) {
                const int row = idx >> 2, kq = (idx & 3) * 4;
                As[kq + 0][row] = aReg[u].x;
                As[kq + 1][row] = aReg[u].y;
                As[kq + 2][row] = aReg[u].z;
                As[kq + 3][row] = aReg[u].w;
            }
        }
#pragma unroll
        for (int u = 0; u < WLOOP; u++) {
            const int idx = tid + u * 256;
            if (idx < WF4) {
                const int row = idx >> 2, kq = (idx & 3) * 4;
                Bs[kq + 0][row] = wReg[u].x;
                Bs[kq + 1][row] = wReg[u].y;
                Bs[kq + 2][row] = wReg[u].z;
                Bs[kq + 3][row] = wReg[u].w;
            }
        }
    };

    issueLoads(0);
    writeLDS();
    __syncthreads();

    const int NT = Kd / 16;
    for (int t = 0; t < NT; t++) {
        if (t + 1 < NT) issueLoads((t + 1) * 16);
#pragma unroll
        for (int k = 0; k < 16; k++) {
            float a[GM * 4], b[GN * 4];
#pragma unroll
            for (int g = 0; g < GM; g++) {
                const float4 t4 = *(const float4*)&As[k][g * 64 + ty * 4];
                a[g * 4 + 0] = t4.x; a[g * 4 + 1] = t4.y;
                a[g * 4 + 2] = t4.z; a[g * 4 + 3] = t4.w;
            }
#pragma unroll
            for (int g = 0; g < GN; g++) {
                const float4 t4 = *(const float4*)&Bs[k][g * 64 + tx * 4];
                b[g * 4 + 0] = t4.x; b[g * 4 + 1] = t4.y;
                b[g * 4 + 2] = t4.z; b[g * 4 + 3] = t4.w;
            }
#pragma unroll
            for (int i = 0; i < GM * 4; i++)
#pragma unroll
                for (int j = 0; j < GN * 4; j++) acc[i][j] += a[i] * b[j];
        }
        __syncthreads();
        if (t + 1 < NT) {
            writeLDS();
            __syncthreads();
        }
    }

#pragma unroll
    for (int i = 0; i < GM * 4; i++) {
        const int m = m0 + (i >> 2) * 64 + ty * 4 + (i & 3);
        if (m >= M) continue;
#pragma unroll
        for (int j = 0; j < GN * 4; j++) {
            const int n = n0 + (j >> 2) * 64 + tx * 4 + (j & 3);
            if (n >= Nout) continue;
            C0[(long)m * Nout + n] = acc[i][j];
        }
    }
}

// softplus(forget_base) per channel (once) -- double (feeds sensitive alpha path)
__global__ __launch_bounds__(256) void spb_kernel(const float* __restrict__ fb,
                                                  double* __restrict__ spb)
{
    int h = blockIdx.x * 256 + threadIdx.x;
    if (h < HID) {
        double xv = (double)fb[h];
        spb[h] = log1p(exp(xv));
    }
}

// causal depthwise conv (one batch), fp32 math, fused fp16-plane split
__global__ __launch_bounds__(256) void conv_kernel(const float* __restrict__ xin,
                                                   const float* __restrict__ cw,
                                                   const float* __restrict__ cb,
                                                   float* __restrict__ outp,
                                                   _Float16* __restrict__ outP,
                                                   size_t ps)
{
    size_t i = (size_t)blockIdx.x * 256 + threadIdx.x;
    if (i >= TH) return;
    int h = (int)(i % HID);
    int t = (int)(i / HID);
    float acc = cb[h];
#pragma unroll
    for (int j = 0; j < KC; j++) {
        int tt = t - (KC - 1) + j;
        if (tt >= 0) acc = fmaf(cw[h * KC + j], xin[(size_t)tt * HID + h], acc);
    }
    outp[i] = acc;
    _Float16 a0, a1;
    hsplit(acc, a0, a1);
    const size_t didx = ((size_t)(h >> 3) * TT + t) * 8 + (h & 7);
    outP[didx] = a0;
    outP[ps + didx] = a1;
}

// raw forget(fg)/inp(ip) (+bias) -> alpha, xh2.  alpha path double, rest fp32.
__global__ __launch_bounds__(256) void alpha_xh2_kernel(float* __restrict__ fg,
                                                        float* __restrict__ ip,
                                                        const float* __restrict__ xh1,
                                                        const double* __restrict__ spb,
                                                        const float* __restrict__ gb)
{
    size_t i = (size_t)blockIdx.x * 256 + threadIdx.x;
    if (i >= TH) return;
    int h = (int)(i % HID);
    double f  = (double)fg[i] + (double)gb[h];
    float g2 = ip[i] + gb[HID + h];
    double sigf = 1.0 / (1.0 + exp(-f));
    float alpha = (float)exp(-8.0 * spb[h] * sigf);
    float s2 = sqrtf(1.0f - alpha * alpha + 1e-6f);
    float sigi = 1.0f / (1.0f + expf(-g2));
    fg[i] = alpha;
    ip[i] = s2 * sigi * xh1[i];
}

// scan pass1 (double accumulation)
__global__ __launch_bounds__(256) void scan1_kernel(const float* __restrict__ alpha,
                                                    const float* __restrict__ xh2,
                                                    double* __restrict__ cA,
                                                    double* __restrict__ cB)
{
    int idx = blockIdx.x * 256 + threadIdx.x;
    if (idx >= NCH * HID) return;
    int h = idx % HID;
    int c = idx / HID;
    size_t base = (size_t)c * CHL * HID + h;
    double aP = 1.0, bV = 0.0;
    for (int i = 0; i < CHL; i++) {
        double a  = (double)alpha[base + (size_t)i * HID];
        double xv = (double)xh2 [base + (size_t)i * HID];
        bV = a * bV + xv;
        aP *= a;
    }
    size_t o = (size_t)c * HID + h;
    cA[o] = aP;
    cB[o] = bV;
}

// scan pass2
__global__ __launch_bounds__(256) void scan2_kernel(const double* __restrict__ cA,
                                                    const double* __restrict__ cB,
                                                    double* __restrict__ cH0)
{
    int h = blockIdx.x * 256 + threadIdx.x;
    if (h >= HID) return;
    double carry = 0.0;
    for (int c = 0; c < NCH; c++) {
        size_t o = (size_t)c * HID + h;
        cH0[o] = carry;
        carry = cA[o] * carry + cB[o];
    }
}

// scan pass3 FUSED with xr = gelu(xh3)*h: replay h on the fly, consume xh3
// (in slotC) in place, write xr fp32 + fp16 planes.  h never materialized.
__global__ __launch_bounds__(256) void scan3gelu_kernel(const float* __restrict__ alpha,
                                                        const float* __restrict__ xh2,
                                                        const double* __restrict__ cH0,
                                                        float* __restrict__ xh3,
                                                        _Float16* __restrict__ outP,
                                                        size_t ps)
{
    int idx = blockIdx.x * 256 + threadIdx.x;
    if (idx >= NCH * HID) return;
    int h = idx % HID;
    int c = idx / HID;
    size_t base = (size_t)c * CHL * HID + h;
    double hv = cH0[(size_t)c * HID + h];
    for (int i = 0; i < CHL; i++) {
        size_t off = base + (size_t)i * HID;
        double a  = (double)alpha[off];
        double xv = (double)xh2 [off];
        hv = a * hv + xv;
        float x3 = xh3[off];
        float ge = 0.5f * x3 * (1.0f + erff(x3 * 0.70710678f));
        float fv = ge * (float)hv;
        xh3[off] = fv;
        _Float16 a0, a1;
        hsplit(fv, a0, a1);
        const int t = c * CHL + i;
        const size_t didx = ((size_t)(h >> 3) * TT + t) * 8 + (h & 7);
        outP[didx] = a0;
        outP[ps + didx] = a1;
    }
}

// attention 1: kv is [T][2*DD], cols [0,DD)=k, [DD,2DD)=v
__global__ __launch_bounds__(256) void attn1_kernel(const float* __restrict__ kv,
                                                    const float* __restrict__ qbuf,
                                                    float* __restrict__ mem)
{
    const int s = blockIdx.x;
    const int l = threadIdx.x;
    const size_t row = (size_t)s * LSEG + l;
    const float* kr = kv + row * (2 * DD);
    const float* qs = qbuf + (size_t)s * DD;
    double acc = 0.0;
    for (int d = 0; d < DD; d++) acc += (double)qs[d] * (double)kr[d];
    double qk = acc / sqrt((double)DD);
    __shared__ double r1[256];
    __shared__ double sw[256];
    r1[l] = qk; __syncthreads();
    for (int off = 128; off > 0; off >>= 1) {
        if (l < off) r1[l] = fmax(r1[l], r1[l + off]);
        __syncthreads();
    }
    double m = r1[0]; __syncthreads();
    double e = exp(qk - m);
    r1[l] = e; __syncthreads();
    for (int off = 128; off > 0; off >>= 1) {
        if (l < off) r1[l] += r1[l + off];
        __syncthreads();
    }
    double denom = r1[0];
    sw[l] = e / denom; __syncthreads();
    const size_t vbase = (size_t)s * LSEG * (2 * DD) + DD;
    for (int d = l; d < DD; d += 256) {
        double a2 = 0.0;
        for (int ll = 0; ll < LSEG; ll++)
            a2 += sw[ll] * (double)kv[vbase + (size_t)ll * (2 * DD) + d];
        mem[(size_t)s * DD + d] = (float)a2;
    }
}

// attention 2 + output gate; rkv combined [16][1920] (rk cols 0..383, rv 384..1919)
__global__ __launch_bounds__(256) void attn2_kernel(const float* __restrict__ rq,
                                                    const float* __restrict__ rkv,
                                                    const float* __restrict__ xr,
                                                    const float* __restrict__ wg,
                                                    _Float16* __restrict__ outP,
                                                    size_t ps)
{
    const int t = blockIdx.x;
    const int sigma = t >> 8;
    const int tid = threadIdx.x;
    __shared__ double sqk[16];
    __shared__ double red[256];
    __shared__ double sw[16];
    __shared__ double sgate;

    const float* rqn = rq + (size_t)t * DD;
    {
        int s = tid >> 4, j = tid & 15;
        const float* rks = rkv + (size_t)s * RKVN;
        double part = 0.0;
        for (int d = j; d < DD; d += 16) part += (double)rqn[d] * (double)rks[d];
#pragma unroll
        for (int off = 8; off > 0; off >>= 1) part += __shfl_down(part, off, 16);
        if (j == 0) sqk[s] = part;
    }
    double gp = 0.0;
    const float* xrn = xr + (size_t)t * HID;
    for (int hh = tid; hh < HID; hh += 256) gp += (double)xrn[hh] * (double)wg[hh];
    red[tid] = gp; __syncthreads();
    for (int off = 128; off > 0; off >>= 1) {
        if (tid < off) red[tid] += red[tid + off];
        __syncthreads();
    }
    if (tid == 0) {
        const double inv = 1.0 / sqrt((double)DD);
        double m = -1e300;
        for (int ss = sigma; ss < 16; ss++) {
            double v = sqk[ss] * inv;
            sqk[ss] = v;
            if (v > m) m = v;
        }
        double sum = 0.0;
        for (int ss = sigma; ss < 16; ss++) {
            double e = exp(sqk[ss] - m);
            sw[ss] = e;
            sum += e;
        }
        double isum = 1.0 / sum;
        for (int ss = 0; ss < sigma; ss++) sw[ss] = 0.0;
        for (int ss = sigma; ss < 16; ss++) sw[ss] *= isum;
        sgate = 1.0 / (1.0 + exp(-red[0]));
    }
    __syncthreads();
    const double gte = sgate;
    for (int c = tid; c < HID / 8; c += 256) {
        double accv[8] = {0, 0, 0, 0, 0, 0, 0, 0};
        for (int ss = sigma; ss < 16; ss++) {
            const float* rvp = rkv + (size_t)ss * RKVN + DD + c * 8;
            double w = sw[ss];
#pragma unroll
            for (int e = 0; e < 8; e++) accv[e] += w * (double)rvp[e];
        }
        h8 h0v, h1v;
#pragma unroll
        for (int e = 0; e < 8; e++) {
            _Float16 a0, a1;
            hsplit((float)(gte * accv[e]), a0, a1);
            h0v[e] = a0; h1v[e] = a1;
        }
        const size_t didx = ((size_t)c * TT + t) * 8;
        *(h8*)(outP + didx) = h0v;
        *(h8*)(outP + ps + didx) = h1v;
    }
}

extern "C" void kernel_launch(void* const* d_in, const int* in_sizes, int n_in,
                              void* d_out, int out_size, void* d_ws, size_t ws_size,
                              hipStream_t stream)
{
    const float* x            = (const float*)d_in[0];
    const float* input_w      = (const float*)d_in[1];
    const float* conv_w       = (const float*)d_in[2];
    const float* conv_b       = (const float*)d_in[3];
    const float* gates_w      = (const float*)d_in[4];
    const float* gates_b      = (const float*)d_in[5];
    const float* forget_base  = (const float*)d_in[6];
    const float* output_w     = (const float*)d_in[7];
    const float* memory_slots = (const float*)d_in[8];
    const float* wq_w         = (const float*)d_in[9];
    const float* wk_w         = (const float*)d_in[10];
    const float* wv_w         = (const float*)d_in[11];
    const float* wg_w         = (const float*)d_in[12];
    const float* rq_w         = (const float*)d_in[13];
    const float* rk_w         = (const float*)d_in[14];
    const float* rv_w         = (const float*)d_in[15];
    float* out = (float*)d_out;

    // ---- workspace layout (~185 MB) ----
    double* spb  = (double*)d_ws;                     // HID
    double* cA   = spb + HID;                         // NCH*HID
    double* cB   = cA + (size_t)NCH * HID;
    double* cH0  = cB + (size_t)NCH * HID;
    float* slotA = (float*)(cH0 + (size_t)NCH * HID); // TH floats each
    float* slotB = slotA + TH;
    float* slotC = slotB + TH;
    float* qbuf   = slotC + TH;                       // 16*384
    float* membuf = qbuf + (size_t)SSEG * DD;         // 16*384
    float* rkvw   = membuf + (size_t)SSEG * DD;       // 1920*384
    float* rkvbuf = rkvw + (size_t)RKVN * DD;         // 16*1920
    float* kvbuf  = rkvbuf + (size_t)SSEG * RKVN;     // TT*768

    _Float16* base_h = (_Float16*)(kvbuf + (size_t)TT * 2 * DD);
    const size_t iwN  = (size_t)HID * DIMW;           // per-half input_w
    const size_t gwN  = (size_t)HID2 * HID;
    const size_t kvN  = (size_t)(2 * DD) * HID;
    const size_t rqN  = (size_t)DD * HID;
    const size_t owN  = (size_t)DIMW * HID;
    const size_t xbN  = (size_t)TT * DIMW;
    _Float16* iwlo = base_h;                          // 2*iwN
    _Float16* iwhi = iwlo + 2 * iwN;
    _Float16* gwp  = iwhi + 2 * iwN;
    _Float16* wkvp = gwp  + 2 * gwN;
    _Float16* rqwp = wkvp + 2 * kvN;
    _Float16* owp  = rqwp + 2 * rqN;
    _Float16* xbP  = owp  + 2 * owN;                  // 2*xbN
    _Float16* P1   = xbP  + 2 * xbN;                  // 2*TH

    dim3 blk(256);
    dim3 blk512(512);
    const int ewBlocks = (int)(TH / 256);

    // ---- one-time: softplus, weight splits/concats, q projection ----
    spb_kernel<<<(HID + 255) / 256, blk, 0, stream>>>(forget_base, spb);
    ccat2_kernel<<<(2 * DD * HID + 255) / 256, blk, 0, stream>>>(
        wk_w, DD * HID, wv_w, DD * HID, slotA);
    ccat2_kernel<<<(RKVN * DD + 255) / 256, blk, 0, stream>>>(
        rk_w, DD * DD, rv_w, HID * DD, rkvw);
    split2t<<<dim3(DIMW / 64, HID / 64), blk, 0, stream>>>(input_w, iwlo, HID, DIMW, iwN);
    split2t<<<dim3(DIMW / 64, HID / 64), blk, 0, stream>>>(input_w + (size_t)HID * DIMW,
                                                           iwhi, HID, DIMW, iwN);
    split2t<<<dim3(HID / 64, HID2 / 64), blk, 0, stream>>>(gates_w, gwp, HID2, HID, gwN);
    split2t<<<dim3(HID / 64, (2 * DD) / 64), blk, 0, stream>>>(slotA, wkvp, 2 * DD, HID, kvN);
    split2t<<<dim3(HID / 64, DD / 64), blk, 0, stream>>>(rq_w, rqwp, DD, HID, rqN);
    split2t<<<dim3(HID / 64, DIMW / 64), blk, 0, stream>>>(output_w, owp, DIMW, HID, owN);
    gemm32<64, 64><<<dim3(1, DD / 64), blk, 0, stream>>>(
        memory_slots, wq_w, qbuf, SSEG, DD, DD);

    for (int b = 0; b < BB; b++) {
        const float* xb   = x   + (size_t)b * TT * DIMW;
        float*       outb = out + (size_t)b * TT * DIMW;

        // split xb once (shared by xh0 GEMM and silu GEMM)
        split2t<<<dim3(DIMW / 64, TT / 64), blk, 0, stream>>>(xb, xbP, TT, DIMW, xbN);
        // xh0 = xb @ input_w[HID:,:].T -> slotB   (grid 384)
        gemm_mfma<0, 128, 128><<<dim3(TT / 128, HID / 128), blk512, 0, stream>>>(
            xbP, xbN, iwhi, iwN, slotB, (float*)nullptr, (const float*)nullptr,
            (_Float16*)nullptr, 0, TT, HID, DIMW);
        // xh1 = causal conv(xh0) -> slotC fp32 + P1 planes (fused split)
        conv_kernel<<<ewBlocks, blk, 0, stream>>>(slotB, conv_w, conv_b, slotC, P1, TH);
        // g = xh1 @ gates_w.T -> forget raw (slotA), inp raw (slotB)  (grid 768)
        gemm_mfma<1, 128, 128><<<dim3(TT / 128, HID2 / 128), blk512, 0, stream>>>(
            P1, TH, gwp, gwN, slotA, slotB, (const float*)nullptr,
            (_Float16*)nullptr, 0, TT, HID2, HID);
        // alpha(slotA), xh2(slotB) in-place, reads xh1(slotC)
        alpha_xh2_kernel<<<ewBlocks, blk, 0, stream>>>(slotA, slotB, slotC, spb, gates_b);
        // scan chunk pass + carries
        scan1_kernel<<<(NCH * HID) / 256, blk, 0, stream>>>(slotA, slotB, cA, cB);
        scan2_kernel<<<(HID + 255) / 256, blk, 0, stream>>>(cA, cB, cH0);
        // xh3 = silu(xb @ input_w[:HID].T) * xh2(slotB) -> slotC (xh1 dead) + P1 planes
        gemm_mfma<2, 128, 128><<<dim3(TT / 128, HID / 128), blk512, 0, stream>>>(
            xbP, xbN, iwlo, iwN, slotC, (float*)nullptr, slotB, P1, TH, TT, HID, DIMW);
        // k|v from xh3 planes -> kvbuf [T][768]   (grid 192)
        gemm_mfma<0, 128, 128><<<dim3(TT / 128, (2 * DD) / 128), blk512, 0, stream>>>(
            P1, TH, wkvp, kvN, kvbuf, (float*)nullptr, (const float*)nullptr,
            (_Float16*)nullptr, 0, TT, 2 * DD, HID);
        // segment attention -> membuf ; rk|rv = mem @ rkv_w.T
        attn1_kernel<<<SSEG, blk, 0, stream>>>(kvbuf, qbuf, membuf);
        gemm32<64, 64><<<dim3(1, (RKVN + 63) / 64), blk, 0, stream>>>(
            membuf, rkvw, rkvbuf, SSEG, RKVN, DD);
        // scan replay fused with gelu: xr -> slotC in-place + P1 planes
        scan3gelu_kernel<<<(NCH * HID) / 256, blk, 0, stream>>>(
            slotA, slotB, cH0, slotC, P1, TH);
        // rq = xr @ rq_w.T -> slotB (xh2 dead)   (64x128 tile, grid 192)
        gemm_mfma<0, 64, 128><<<dim3(TT / 64, DD / 128), blk512, 0, stream>>>(
            P1, TH, rqwp, rqN, slotB, (float*)nullptr, (const float*)nullptr,
            (_Float16*)nullptr, 0, TT, DD, HID);
        // cross attention + gate -> fp16 planes in P1 directly
        attn2_kernel<<<TT, blk, 0, stream>>>(slotB, rkvbuf, slotC, wg_w, P1, TH);
        // final projection -> d_out   (grid 256)
        gemm_mfma<0, 128, 128><<<dim3(TT / 128, DIMW / 128), blk512, 0, stream>>>(
            P1, TH, owp, owN, outb, (float*)nullptr, (const float*)nullptr,
            (_Float16*)nullptr, 0, TT, DIMW, HID);
    }
}

// Round 9
// 2414.729 us; speedup vs baseline: 1.1475x; 1.0245x over previous
//
#include <hip/hip_runtime.h>
#include <math.h>

#define BB 4
#define TT 4096
#define DIMW 1024
#define HID 1536
#define HID2 3072
#define KC 4
#define SSEG 16
#define LSEG 256
#define DD 384
#define NCH 64          // scan chunks per batch
#define CHL 64          // tokens per chunk (NCH*CHL == TT)
#define TH  ((size_t)TT*(size_t)HID)   // elements in one T x HID slot
#define RKVN (DD + HID) // 1920 rows of merged rk|rv weight

typedef _Float16 h8 __attribute__((ext_vector_type(8)));
typedef float f4 __attribute__((ext_vector_type(4)));

#define RSCL 4.8828125e-4f   // 2^-11

// fp16 2-plane split with scaled residual: a ~= h0 + h1 * 2^-11.
__device__ __forceinline__ void hsplit(float a, _Float16& h0, _Float16& h1)
{
    _Float16 t = (_Float16)a;
    float tf = (float)t;
    if (fabsf(tf) < 6.103515625e-05f) { t = (_Float16)0.f; tf = 0.f; }
    h0 = t;
    h1 = (_Float16)((a - tf) * 2048.0f);
}

// async global->LDS, 16B per lane
__device__ __forceinline__ void gl_lds16(const _Float16* g, _Float16* l)
{
    __builtin_amdgcn_global_load_lds(
        (const __attribute__((address_space(1))) unsigned int*)g,
        (__attribute__((address_space(3))) unsigned int*)l,
        16, 0, 0);
}

// =====================================================================
// LDS-transpose split: fp32 [R][Kd] -> 2 fp16 planes kcm (weights + xb)
// =====================================================================
__global__ __launch_bounds__(256) void split2t(const float* __restrict__ src,
                                               _Float16* __restrict__ dst,
                                               int R, int Kd, size_t ps)
{
    __shared__ float tile[64][65];
    const int tid = threadIdx.x;
    const int bx = blockIdx.x;
    const int by = blockIdx.y;
    {
        const int lr = tid >> 2;
        const int lc = (tid & 3) * 16;
        const float* s = src + (size_t)(by * 64 + lr) * Kd + bx * 64 + lc;
#pragma unroll
        for (int e = 0; e < 16; e++) tile[lr][lc + e] = s[e];
    }
    __syncthreads();
    const int c = tid >> 5;
    const int r0 = tid & 31;
#pragma unroll
    for (int rr = 0; rr < 2; rr++) {
        const int r = r0 + rr * 32;
        h8 h0v, h1v;
#pragma unroll
        for (int e = 0; e < 8; e++) {
            _Float16 a0, a1;
            hsplit(tile[r][c * 8 + e], a0, a1);
            h0v[e] = a0; h1v[e] = a1;
        }
        const size_t didx = ((size_t)(bx * 8 + c) * R + by * 64 + r) * 8;
        *(h8*)(dst + didx) = h0v;
        *(h8*)(dst + ps + didx) = h1v;
    }
}

// generic 2-buffer row-concat: dst[0..n1) = s1, dst[n1..n1+n2) = s2
__global__ __launch_bounds__(256) void ccat2_kernel(const float* __restrict__ s1, int n1,
                                                    const float* __restrict__ s2, int n2,
                                                    float* __restrict__ dst)
{
    int i = blockIdx.x * 256 + threadIdx.x;
    if (i < n1) dst[i] = s1[i];
    else if (i < n1 + n2) dst[i] = s2[i - n1];
}

// =====================================================================
// 2-buffer fp16x2 MFMA GEMM, 8 waves (2x4): C = A @ W^T
// Both operands 2 fp16 planes (scaled residual, kcm).  3 MFMA products,
// dual accumulators, stage-issued-before-compute, one barrier per K-step,
// global_load_lds staging.
// Block ordering: XCD-chunked + 2x2 SUPERTILES within each XCD chunk so
// temporally adjacent blocks share A/B panels in the 4MB per-XCD L2
// (A+B working set of a supertile ~3.2MB < 4MB; flat ordering streamed
// 25MB A-panels through L2 -> 274MB FETCH_SIZE on gates).
// MODE 0: plain store (row stride Nout)
// MODE 1: split cols at HID -> C0/C1 (both stride HID)
// MODE 2: C0 = silu(acc)*X, + fused fp16-plane split of C0 into OP
// =====================================================================
template<int MODE, int TM, int TN>
__global__ __launch_bounds__(512, 4) void gemm_mfma(
    const _Float16* __restrict__ Ap, size_t aps,
    const _Float16* __restrict__ Wp, size_t wps,
    float* __restrict__ C0, float* __restrict__ C1,
    const float* __restrict__ X,
    _Float16* __restrict__ OP, size_t ops,
    int M, int Nout, int Kd)
{
    constexpr int WTM = TM / 2, WTN = TN / 4;
    constexpr int MI = WTM / 16, NI = WTN / 16;
    static_assert(MI * NI <= 16, "DUAL only");
    constexpr int API = TM / 16;
    constexpr int BPI = TN / 16;
    constexpr int ATOT = 2 * API;
    constexpr int NISS = ATOT + 2 * BPI;
    static_assert(NISS % 8 == 0, "issue count must divide 8 waves");
    constexpr int PW = NISS / 8;

    __shared__ _Float16 Als[2][2][TM * 32];
    __shared__ _Float16 Bls[2][2][TN * 32];

    const int tid = threadIdx.x;
    const int lane = tid & 63;
    const int wv = tid >> 6;
    const int wr = wv >> 2, wc = wv & 3;
    const int lr = lane & 15, lg = lane >> 4;

    int bx = blockIdx.x, by = blockIdx.y;
    {
        const int gx = gridDim.x, gy = gridDim.y;
        const int nwg = gx * gy;
        if (((gx & 1) | (gy & 1)) == 0 && (nwg & 31) == 0) {
            // supertile path: wg -> (xcd, t); S = global supertile, w = quadrant
            int wg = by * gx + bx;
            const int xcd = wg & 7;
            const int t = wg >> 3;
            const int S = xcd * (nwg >> 5) + (t >> 2);
            const int w = t & 3;
            const int sgx = gx >> 1;
            bx = (S % sgx) * 2 + (w & 1);
            by = (S / sgx) * 2 + (w >> 1);
        } else if ((nwg & 7) == 0) {
            int wg = by * gx + bx;
            wg = (wg & 7) * (nwg >> 3) + (wg >> 3);
            bx = wg % gx; by = wg / gx;
        }
    }
    const int m0 = bx * TM, n0 = by * TN;

    f4 acc1[MI][NI], acc2[MI][NI];
#pragma unroll
    for (int i = 0; i < MI; i++)
#pragma unroll
        for (int j = 0; j < NI; j++) {
            acc1[i][j] = (f4){0.f, 0.f, 0.f, 0.f};
            acc2[i][j] = (f4){0.f, 0.f, 0.f, 0.f};
        }

    auto stage = [&](int kq0, int buf) {
#pragma unroll
        for (int j = 0; j < PW; j++) {
            const int i = j * 8 + wv;
            if (i < ATOT) {
                const int pl = i / API, s = i - pl * API;
                const int kc = (s * 64) / TM, r0 = (s * 64) % TM;
                gl_lds16(Ap + pl * aps + ((size_t)(kq0 + kc) * M + m0 + r0) * 8 + lane * 8,
                         &Als[buf][pl][(kc * TM + r0) * 8]);
            } else {
                const int jj = i - ATOT;
                const int pl = jj / BPI, s = jj - pl * BPI;
                const int kc = (s * 64) / TN, r0 = (s * 64) % TN;
                gl_lds16(Wp + pl * wps + ((size_t)(kq0 + kc) * Nout + n0 + r0) * 8 + lane * 8,
                         &Bls[buf][pl][(kc * TN + r0) * 8]);
            }
        }
    };

    stage(0, 0);
    __syncthreads();

    const int NS = Kd / 32;
    for (int t = 0; t < NS; t++) {
        const int buf = t & 1;
        if (t + 1 < NS) stage((t + 1) * 4, buf ^ 1);   // issue BEFORE compute

        h8 af0[MI], af1[MI];
#pragma unroll
        for (int mi = 0; mi < MI; mi++) {
            const int arow = wr * WTM + mi * 16 + lr;
            af0[mi] = *(const h8*)&Als[buf][0][(lg * TM + arow) * 8];
            af1[mi] = *(const h8*)&Als[buf][1][(lg * TM + arow) * 8];
        }
#pragma unroll
        for (int ni = 0; ni < NI; ni++) {
            const int brow = wc * WTN + ni * 16 + lr;
            h8 b0 = *(const h8*)&Bls[buf][0][(lg * TN + brow) * 8];
            h8 b1 = *(const h8*)&Bls[buf][1][(lg * TN + brow) * 8];
#pragma unroll
            for (int mi = 0; mi < MI; mi++) {
                acc1[mi][ni] = __builtin_amdgcn_mfma_f32_16x16x32_f16(af0[mi], b0, acc1[mi][ni], 0, 0, 0);
                acc2[mi][ni] = __builtin_amdgcn_mfma_f32_16x16x32_f16(af1[mi], b0, acc2[mi][ni], 0, 0, 0);
                acc2[mi][ni] = __builtin_amdgcn_mfma_f32_16x16x32_f16(af0[mi], b1, acc2[mi][ni], 0, 0, 0);
            }
        }
        __syncthreads();   // drains staged loads; next iter reads buf^1 safely
    }

#pragma unroll
    for (int mi = 0; mi < MI; mi++) {
#pragma unroll
        for (int ni = 0; ni < NI; ni++) {
#pragma unroll
            for (int r = 0; r < 4; r++) {
                const float v = acc1[mi][ni][r] + acc2[mi][ni][r] * RSCL;
                const int m = m0 + wr * WTM + mi * 16 + lg * 4 + r;
                const int n = n0 + wc * WTN + ni * 16 + lr;
                if constexpr (MODE == 1) {
                    if (n < HID) C0[(size_t)m * HID + n] = v;
                    else         C1[(size_t)m * HID + (n - HID)] = v;
                } else if constexpr (MODE == 2) {
                    float g = v;
                    float fv = (g / (1.0f + expf(-g))) * X[(size_t)m * Nout + n];
                    C0[(size_t)m * Nout + n] = fv;
                    _Float16 a0, a1;
                    hsplit(fv, a0, a1);
                    const size_t didx = ((size_t)(n >> 3) * M + m) * 8 + (n & 7);
                    OP[didx] = a0;
                    OP[ops + didx] = a1;
                } else {
                    C0[(size_t)m * Nout + n] = v;
                }
            }
        }
    }
}

// =====================================================================
// fp32 VALU GEMM kept only for tiny M=16 matmuls (q, rkv)
// =====================================================================
template<int TM, int TN>
__global__ __launch_bounds__(256) void gemm32(const float* __restrict__ A,
                                              const float* __restrict__ W,
                                              float* __restrict__ C0,
                                              int M, int Nout, int Kd)
{
    constexpr int GM = TM / 64;
    constexpr int GN = TN / 64;
    constexpr int AF4 = TM * 4;
    constexpr int WF4 = TN * 4;
    constexpr int ALOOP = (AF4 + 255) / 256;
    constexpr int WLOOP = (WF4 + 255) / 256;

    __shared__ float As[16][TM];
    __shared__ float Bs[16][TN];

    const int tid = threadIdx.x;
    const int m0 = blockIdx.x * TM;
    const int n0 = blockIdx.y * TN;
    const int tx = tid & 15, ty = tid >> 4;

    float acc[GM * 4][GN * 4];
#pragma unroll
    for (int i = 0; i < GM * 4; i++)
#pragma unroll
        for (int j = 0; j < GN * 4; j++) acc[i][j] = 0.0f;

    float4 aReg[ALOOP], wReg[WLOOP];

    auto issueLoads = [&](int k0) {
#pragma unroll
        for (int u = 0; u < ALOOP; u++) {
            const int idx = tid + u * 256;
            float4 v = make_float4(0.f, 0.f, 0.f, 0.f);
            if (idx < AF4) {
                const int row = idx >> 2, kq = (idx & 3) * 4;
                const long ar = (long)(m0 + row);
                if (ar < M) v = *(const float4*)(A + ar * (long)Kd + (k0 + kq));
            }
            aReg[u] = v;
        }
#pragma unroll
        for (int u = 0; u < WLOOP; u++) {
            const int idx = tid + u * 256;
            float4 v = make_float4(0.f, 0.f, 0.f, 0.f);
            if (idx < WF4) {
                const int row = idx >> 2, kq = (idx & 3) * 4;
                const long wr = (long)(n0 + row);
                if (wr < Nout) v = *(const float4*)(W + wr * (long)Kd + (k0 + kq));
            }
            wReg[u] = v;
        }
    };
    auto writeLDS = [&]() {
#pragma unroll
        for (int u = 0; u < ALOOP; u++) {
            const int idx = tid + u * 256;
            if (idx < AF4) {
                const int row = idx >> 2, kq = (idx & 3) * 4;
                As[kq + 0][row] = aReg[u].x;
                As[kq + 1][row] = aReg[u].y;
                As[kq + 2][row] = aReg[u].z;
                As[kq + 3][row] = aReg[u].w;
            }
        }
#pragma unroll
        for (int u = 0; u < WLOOP; u++) {
            const int idx = tid + u * 256;
            if (idx < WF4) {
                const int row = idx >> 2, kq = (idx & 3) * 4;
                Bs[kq + 0][row] = wReg[u].x;
                Bs[kq + 1][row] = wReg[u].y;
                Bs[kq + 2][row] = wReg[u].z;
                Bs[kq + 3][row] = wReg[u].w;
            }
        }
    };

    issueLoads(0);
    writeLDS();
    __syncthreads();

    const int NT = Kd / 16;
    for (int t = 0; t < NT; t++) {
        if (t + 1 < NT) issueLoads((t + 1) * 16);
#pragma unroll
        for (int k = 0; k < 16; k++) {
            float a[GM * 4], b[GN * 4];
#pragma unroll
            for (int g = 0; g < GM; g++) {
                const float4 t4 = *(const float4*)&As[k][g * 64 + ty * 4];
                a[g * 4 + 0] = t4.x; a[g * 4 + 1] = t4.y;
                a[g * 4 + 2] = t4.z; a[g * 4 + 3] = t4.w;
            }
#pragma unroll
            for (int g = 0; g < GN; g++) {
                const float4 t4 = *(const float4*)&Bs[k][g * 64 + tx * 4];
                b[g * 4 + 0] = t4.x; b[g * 4 + 1] = t4.y;
                b[g * 4 + 2] = t4.z; b[g * 4 + 3] = t4.w;
            }
#pragma unroll
            for (int i = 0; i < GM * 4; i++)
#pragma unroll
                for (int j = 0; j < GN * 4; j++) acc[i][j] += a[i] * b[j];
        }
        __syncthreads();
        if (t + 1 < NT) {
            writeLDS();
            __syncthreads();
        }
    }

#pragma unroll
    for (int i = 0; i < GM * 4; i++) {
        const int m = m0 + (i >> 2) * 64 + ty * 4 + (i & 3);
        if (m >= M) continue;
#pragma unroll
        for (int j = 0; j < GN * 4; j++) {
            const int n = n0 + (j >> 2) * 64 + tx * 4 + (j & 3);
            if (n >= Nout) continue;
            C0[(long)m * Nout + n] = acc[i][j];
        }
    }
}

// softplus(forget_base) per channel (once) -- double (feeds sensitive alpha path)
__global__ __launch_bounds__(256) void spb_kernel(const float* __restrict__ fb,
                                                  double* __restrict__ spb)
{
    int h = blockIdx.x * 256 + threadIdx.x;
    if (h < HID) {
        double xv = (double)fb[h];
        spb[h] = log1p(exp(xv));
    }
}

// causal depthwise conv (one batch), fp32 math, fused fp16-plane split
__global__ __launch_bounds__(256) void conv_kernel(const float* __restrict__ xin,
                                                   const float* __restrict__ cw,
                                                   const float* __restrict__ cb,
                                                   float* __restrict__ outp,
                                                   _Float16* __restrict__ outP,
                                                   size_t ps)
{
    size_t i = (size_t)blockIdx.x * 256 + threadIdx.x;
    if (i >= TH) return;
    int h = (int)(i % HID);
    int t = (int)(i / HID);
    float acc = cb[h];
#pragma unroll
    for (int j = 0; j < KC; j++) {
        int tt = t - (KC - 1) + j;
        if (tt >= 0) acc = fmaf(cw[h * KC + j], xin[(size_t)tt * HID + h], acc);
    }
    outp[i] = acc;
    _Float16 a0, a1;
    hsplit(acc, a0, a1);
    const size_t didx = ((size_t)(h >> 3) * TT + t) * 8 + (h & 7);
    outP[didx] = a0;
    outP[ps + didx] = a1;
}

// FUSED: raw forget(fg)/inp(ip) (+bias) -> alpha,xh2 AND scan pass1.
// One thread per (chunk c, channel h): serial over the 64 tokens of the
// chunk (same order scan1 used), writing alpha/xh2 in passing.  Removes
// the 50MB alpha/xh2 re-read the separate scan1 pass did.
// alpha chain in double (scan amplifies by 1/(1-alpha)); rest fp32.
__global__ __launch_bounds__(256) void alphascan1_kernel(float* __restrict__ fg,
                                                         float* __restrict__ ip,
                                                         const float* __restrict__ xh1,
                                                         const double* __restrict__ spb,
                                                         const float* __restrict__ gb,
                                                         double* __restrict__ cA,
                                                         double* __restrict__ cB)
{
    int idx = blockIdx.x * 256 + threadIdx.x;
    if (idx >= NCH * HID) return;
    int h = idx % HID;
    int c = idx / HID;
    const double spbh = spb[h];
    const float gbf = gb[h];
    const float gbi = gb[HID + h];
    size_t base = (size_t)c * CHL * HID + h;
    double aP = 1.0, bV = 0.0;
    for (int i = 0; i < CHL; i++) {
        size_t off = base + (size_t)i * HID;
        double f = (double)fg[off] + (double)gbf;
        float g2 = ip[off] + gbi;
        double sigf = 1.0 / (1.0 + exp(-f));
        double alpha = exp(-8.0 * spbh * sigf);
        float af = (float)alpha;
        float s2 = sqrtf(1.0f - af * af + 1e-6f);
        float sigi = 1.0f / (1.0f + expf(-g2));
        float x2 = s2 * sigi * xh1[off];
        fg[off] = af;
        ip[off] = x2;
        bV = (double)af * bV + (double)x2;
        aP *= (double)af;
    }
    size_t o = (size_t)c * HID + h;
    cA[o] = aP;
    cB[o] = bV;
}

// scan pass2
__global__ __launch_bounds__(256) void scan2_kernel(const double* __restrict__ cA,
                                                    const double* __restrict__ cB,
                                                    double* __restrict__ cH0)
{
    int h = blockIdx.x * 256 + threadIdx.x;
    if (h >= HID) return;
    double carry = 0.0;
    for (int c = 0; c < NCH; c++) {
        size_t o = (size_t)c * HID + h;
        cH0[o] = carry;
        carry = cA[o] * carry + cB[o];
    }
}

// scan pass3 FUSED with xr = gelu(xh3)*h: replay h on the fly, consume xh3
// (in slotC) in place, write xr fp32 + fp16 planes.  h never materialized.
__global__ __launch_bounds__(256) void scan3gelu_kernel(const float* __restrict__ alpha,
                                                        const float* __restrict__ xh2,
                                                        const double* __restrict__ cH0,
                                                        float* __restrict__ xh3,
                                                        _Float16* __restrict__ outP,
                                                        size_t ps)
{
    int idx = blockIdx.x * 256 + threadIdx.x;
    if (idx >= NCH * HID) return;
    int h = idx % HID;
    int c = idx / HID;
    size_t base = (size_t)c * CHL * HID + h;
    double hv = cH0[(size_t)c * HID + h];
    for (int i = 0; i < CHL; i++) {
        size_t off = base + (size_t)i * HID;
        double a  = (double)alpha[off];
        double xv = (double)xh2 [off];
        hv = a * hv + xv;
        float x3 = xh3[off];
        float ge = 0.5f * x3 * (1.0f + erff(x3 * 0.70710678f));
        float fv = ge * (float)hv;
        xh3[off] = fv;
        _Float16 a0, a1;
        hsplit(fv, a0, a1);
        const int t = c * CHL + i;
        const size_t didx = ((size_t)(h >> 3) * TT + t) * 8 + (h & 7);
        outP[didx] = a0;
        outP[ps + didx] = a1;
    }
}

// attention 1: kv is [T][2*DD], cols [0,DD)=k, [DD,2DD)=v
__global__ __launch_bounds__(256) void attn1_kernel(const float* __restrict__ kv,
                                                    const float* __restrict__ qbuf,
                                                    float* __restrict__ mem)
{
    const int s = blockIdx.x;
    const int l = threadIdx.x;
    const size_t row = (size_t)s * LSEG + l;
    const float* kr = kv + row * (2 * DD);
    const float* qs = qbuf + (size_t)s * DD;
    double acc = 0.0;
    for (int d = 0; d < DD; d++) acc += (double)qs[d] * (double)kr[d];
    double qk = acc / sqrt((double)DD);
    __shared__ double r1[256];
    __shared__ double sw[256];
    r1[l] = qk; __syncthreads();
    for (int off = 128; off > 0; off >>= 1) {
        if (l < off) r1[l] = fmax(r1[l], r1[l + off]);
        __syncthreads();
    }
    double m = r1[0]; __syncthreads();
    double e = exp(qk - m);
    r1[l] = e; __syncthreads();
    for (int off = 128; off > 0; off >>= 1) {
        if (l < off) r1[l] += r1[l + off];
        __syncthreads();
    }
    double denom = r1[0];
    sw[l] = e / denom; __syncthreads();
    const size_t vbase = (size_t)s * LSEG * (2 * DD) + DD;
    for (int d = l; d < DD; d += 256) {
        double a2 = 0.0;
        for (int ll = 0; ll < LSEG; ll++)
            a2 += sw[ll] * (double)kv[vbase + (size_t)ll * (2 * DD) + d];
        mem[(size_t)s * DD + d] = (float)a2;
    }
}

// attention 2 + output gate; rkv combined [16][1920] (rk cols 0..383, rv 384..1919)
__global__ __launch_bounds__(256) void attn2_kernel(const float* __restrict__ rq,
                                                    const float* __restrict__ rkv,
                                                    const float* __restrict__ xr,
                                                    const float* __restrict__ wg,
                                                    _Float16* __restrict__ outP,
                                                    size_t ps)
{
    const int t = blockIdx.x;
    const int sigma = t >> 8;
    const int tid = threadIdx.x;
    __shared__ double sqk[16];
    __shared__ double red[256];
    __shared__ double sw[16];
    __shared__ double sgate;

    const float* rqn = rq + (size_t)t * DD;
    {
        int s = tid >> 4, j = tid & 15;
        const float* rks = rkv + (size_t)s * RKVN;
        double part = 0.0;
        for (int d = j; d < DD; d += 16) part += (double)rqn[d] * (double)rks[d];
#pragma unroll
        for (int off = 8; off > 0; off >>= 1) part += __shfl_down(part, off, 16);
        if (j == 0) sqk[s] = part;
    }
    double gp = 0.0;
    const float* xrn = xr + (size_t)t * HID;
    for (int hh = tid; hh < HID; hh += 256) gp += (double)xrn[hh] * (double)wg[hh];
    red[tid] = gp; __syncthreads();
    for (int off = 128; off > 0; off >>= 1) {
        if (tid < off) red[tid] += red[tid + off];
        __syncthreads();
    }
    if (tid == 0) {
        const double inv = 1.0 / sqrt((double)DD);
        double m = -1e300;
        for (int ss = sigma; ss < 16; ss++) {
            double v = sqk[ss] * inv;
            sqk[ss] = v;
            if (v > m) m = v;
        }
        double sum = 0.0;
        for (int ss = sigma; ss < 16; ss++) {
            double e = exp(sqk[ss] - m);
            sw[ss] = e;
            sum += e;
        }
        double isum = 1.0 / sum;
        for (int ss = 0; ss < sigma; ss++) sw[ss] = 0.0;
        for (int ss = sigma; ss < 16; ss++) sw[ss] *= isum;
        sgate = 1.0 / (1.0 + exp(-red[0]));
    }
    __syncthreads();
    const double gte = sgate;
    for (int c = tid; c < HID / 8; c += 256) {
        double accv[8] = {0, 0, 0, 0, 0, 0, 0, 0};
        for (int ss = sigma; ss < 16; ss++) {
            const float* rvp = rkv + (size_t)ss * RKVN + DD + c * 8;
            double w = sw[ss];
#pragma unroll
            for (int e = 0; e < 8; e++) accv[e] += w * (double)rvp[e];
        }
        h8 h0v, h1v;
#pragma unroll
        for (int e = 0; e < 8; e++) {
            _Float16 a0, a1;
            hsplit((float)(gte * accv[e]), a0, a1);
            h0v[e] = a0; h1v[e] = a1;
        }
        const size_t didx = ((size_t)c * TT + t) * 8;
        *(h8*)(outP + didx) = h0v;
        *(h8*)(outP + ps + didx) = h1v;
    }
}

extern "C" void kernel_launch(void* const* d_in, const int* in_sizes, int n_in,
                              void* d_out, int out_size, void* d_ws, size_t ws_size,
                              hipStream_t stream)
{
    const float* x            = (const float*)d_in[0];
    const float* input_w      = (const float*)d_in[1];
    const float* conv_w       = (const float*)d_in[2];
    const float* conv_b       = (const float*)d_in[3];
    const float* gates_w      = (const float*)d_in[4];
    const float* gates_b      = (const float*)d_in[5];
    const float* forget_base  = (const float*)d_in[6];
    const float* output_w     = (const float*)d_in[7];
    const float* memory_slots = (const float*)d_in[8];
    const float* wq_w         = (const float*)d_in[9];
    const float* wk_w         = (const float*)d_in[10];
    const float* wv_w         = (const float*)d_in[11];
    const float* wg_w         = (const float*)d_in[12];
    const float* rq_w         = (const float*)d_in[13];
    const float* rk_w         = (const float*)d_in[14];
    const float* rv_w         = (const float*)d_in[15];
    float* out = (float*)d_out;

    // ---- workspace layout (~185 MB) ----
    double* spb  = (double*)d_ws;                     // HID
    double* cA   = spb + HID;                         // NCH*HID
    double* cB   = cA + (size_t)NCH * HID;
    double* cH0  = cB + (size_t)NCH * HID;
    float* slotA = (float*)(cH0 + (size_t)NCH * HID); // TH floats each
    float* slotB = slotA + TH;
    float* slotC = slotB + TH;
    float* qbuf   = slotC + TH;                       // 16*384
    float* membuf = qbuf + (size_t)SSEG * DD;         // 16*384
    float* rkvw   = membuf + (size_t)SSEG * DD;       // 1920*384
    float* rkvbuf = rkvw + (size_t)RKVN * DD;         // 16*1920
    float* kvbuf  = rkvbuf + (size_t)SSEG * RKVN;     // TT*768

    _Float16* base_h = (_Float16*)(kvbuf + (size_t)TT * 2 * DD);
    const size_t iwN  = (size_t)HID * DIMW;           // per-half input_w
    const size_t gwN  = (size_t)HID2 * HID;
    const size_t kvN  = (size_t)(2 * DD) * HID;
    const size_t rqN  = (size_t)DD * HID;
    const size_t owN  = (size_t)DIMW * HID;
    const size_t xbN  = (size_t)TT * DIMW;
    _Float16* iwlo = base_h;                          // 2*iwN
    _Float16* iwhi = iwlo + 2 * iwN;
    _Float16* gwp  = iwhi + 2 * iwN;
    _Float16* wkvp = gwp  + 2 * gwN;
    _Float16* rqwp = wkvp + 2 * kvN;
    _Float16* owp  = rqwp + 2 * rqN;
    _Float16* xbP  = owp  + 2 * owN;                  // 2*xbN
    _Float16* P1   = xbP  + 2 * xbN;                  // 2*TH

    dim3 blk(256);
    dim3 blk512(512);
    const int ewBlocks = (int)(TH / 256);

    // ---- one-time: softplus, weight splits/concats, q projection ----
    spb_kernel<<<(HID + 255) / 256, blk, 0, stream>>>(forget_base, spb);
    ccat2_kernel<<<(2 * DD * HID + 255) / 256, blk, 0, stream>>>(
        wk_w, DD * HID, wv_w, DD * HID, slotA);
    ccat2_kernel<<<(RKVN * DD + 255) / 256, blk, 0, stream>>>(
        rk_w, DD * DD, rv_w, HID * DD, rkvw);
    split2t<<<dim3(DIMW / 64, HID / 64), blk, 0, stream>>>(input_w, iwlo, HID, DIMW, iwN);
    split2t<<<dim3(DIMW / 64, HID / 64), blk, 0, stream>>>(input_w + (size_t)HID * DIMW,
                                                           iwhi, HID, DIMW, iwN);
    split2t<<<dim3(HID / 64, HID2 / 64), blk, 0, stream>>>(gates_w, gwp, HID2, HID, gwN);
    split2t<<<dim3(HID / 64, (2 * DD) / 64), blk, 0, stream>>>(slotA, wkvp, 2 * DD, HID, kvN);
    split2t<<<dim3(HID / 64, DD / 64), blk, 0, stream>>>(rq_w, rqwp, DD, HID, rqN);
    split2t<<<dim3(HID / 64, DIMW / 64), blk, 0, stream>>>(output_w, owp, DIMW, HID, owN);
    gemm32<64, 64><<<dim3(1, DD / 64), blk, 0, stream>>>(
        memory_slots, wq_w, qbuf, SSEG, DD, DD);

    for (int b = 0; b < BB; b++) {
        const float* xb   = x   + (size_t)b * TT * DIMW;
        float*       outb = out + (size_t)b * TT * DIMW;

        // split xb once (shared by xh0 GEMM and silu GEMM)
        split2t<<<dim3(DIMW / 64, TT / 64), blk, 0, stream>>>(xb, xbP, TT, DIMW, xbN);
        // xh0 = xb @ input_w[HID:,:].T -> slotB   (grid 384)
        gemm_mfma<0, 128, 128><<<dim3(TT / 128, HID / 128), blk512, 0, stream>>>(
            xbP, xbN, iwhi, iwN, slotB, (float*)nullptr, (const float*)nullptr,
            (_Float16*)nullptr, 0, TT, HID, DIMW);
        // xh1 = causal conv(xh0) -> slotC fp32 + P1 planes (fused split)
        conv_kernel<<<ewBlocks, blk, 0, stream>>>(slotB, conv_w, conv_b, slotC, P1, TH);
        // g = xh1 @ gates_w.T -> forget raw (slotA), inp raw (slotB)  (grid 768)
        gemm_mfma<1, 128, 128><<<dim3(TT / 128, HID2 / 128), blk512, 0, stream>>>(
            P1, TH, gwp, gwN, slotA, slotB, (const float*)nullptr,
            (_Float16*)nullptr, 0, TT, HID2, HID);
        // fused alpha/xh2 + scan pass1  (alpha->slotA, xh2->slotB in place)
        alphascan1_kernel<<<(NCH * HID) / 256, blk, 0, stream>>>(
            slotA, slotB, slotC, spb, gates_b, cA, cB);
        scan2_kernel<<<(HID + 255) / 256, blk, 0, stream>>>(cA, cB, cH0);
        // xh3 = silu(xb @ input_w[:HID].T) * xh2(slotB) -> slotC (xh1 dead) + P1 planes
        gemm_mfma<2, 128, 128><<<dim3(TT / 128, HID / 128), blk512, 0, stream>>>(
            xbP, xbN, iwlo, iwN, slotC, (float*)nullptr, slotB, P1, TH, TT, HID, DIMW);
        // k|v from xh3 planes -> kvbuf [T][768]   (64x128 tile, grid 384)
        gemm_mfma<0, 64, 128><<<dim3(TT / 64, (2 * DD) / 128), blk512, 0, stream>>>(
            P1, TH, wkvp, kvN, kvbuf, (float*)nullptr, (const float*)nullptr,
            (_Float16*)nullptr, 0, TT, 2 * DD, HID);
        // segment attention -> membuf ; rk|rv = mem @ rkv_w.T
        attn1_kernel<<<SSEG, blk, 0, stream>>>(kvbuf, qbuf, membuf);
        gemm32<64, 64><<<dim3(1, (RKVN + 63) / 64), blk, 0, stream>>>(
            membuf, rkvw, rkvbuf, SSEG, RKVN, DD);
        // scan replay fused with gelu: xr -> slotC in-place + P1 planes
        scan3gelu_kernel<<<(NCH * HID) / 256, blk, 0, stream>>>(
            slotA, slotB, cH0, slotC, P1, TH);
        // rq = xr @ rq_w.T -> slotB (xh2 dead)   (64x128 tile, grid 192)
        gemm_mfma<0, 64, 128><<<dim3(TT / 64, DD / 128), blk512, 0, stream>>>(
            P1, TH, rqwp, rqN, slotB, (float*)nullptr, (const float*)nullptr,
            (_Float16*)nullptr, 0, TT, DD, HID);
        // cross attention + gate -> fp16 planes in P1 directly
        attn2_kernel<<<TT, blk, 0, stream>>>(slotB, rkvbuf, slotC, wg_w, P1, TH);
        // final projection -> d_out   (grid 256)
        gemm_mfma<0, 128, 128><<<dim3(TT / 128, DIMW / 128), blk512, 0, stream>>>(
            P1, TH, owp, owN, outb, (float*)nullptr, (const float*)nullptr,
            (_Float16*)nullptr, 0, TT, DIMW, HID);
    }
}